// Round 15
// baseline (814.939 us; speedup 1.0000x reference)
//
#include <hip/hip_runtime.h>
#include <hip/hip_bf16.h>
#include <math.h>

#define BB   128
#define NN   512
#define DIN  64
#define HH   256
#define DOUT 64
#define BNR  (BB * NN)          // 65536 rows

typedef float  f32x4  __attribute__((ext_vector_type(4)));
typedef __bf16 bf16x8 __attribute__((ext_vector_type(8)));

#define GLP(p)  ((const __attribute__((address_space(1))) void*)(p))
#define LDSP(p) ((__attribute__((address_space(3))) void*)(p))

// Haar/db1 'zero' DWT patterns, levels 1..3, FULL_LEN=8
__constant__ float PAT[3][8] = {
    {0.70710678f, 0.70710678f, 0.f, 0.f, 0.f, 0.f, 0.f, 0.f},
    {0.5f,        0.70710678f, 0.f, 0.5f, 0.f, 0.f, 0.f, 0.f},
    {0.35355339f, 0.70710678f, 0.f, 0.f, 0.f, 0.5f, 0.f, 0.35355339f}
};

__device__ __forceinline__ unsigned short f2bfu(float x) {
    __hip_bfloat16 b = __float2bfloat16(x);
    unsigned short u;
    __builtin_memcpy(&u, &b, 2);
    return u;
}
__device__ __forceinline__ float bf2f(unsigned short u) {
    unsigned int v = ((unsigned int)u) << 16;
    float f;
    __builtin_memcpy(&f, &v, 4);
    return f;
}

// ---------------------------------------------------------------------------
// In-kernel th = sigmoid(mean diff) — same tree order everywhere.
// ---------------------------------------------------------------------------
__device__ __forceinline__ float block_th(const float* __restrict__ partial, int np,
                                          float inv_n, float* red, int tid)
{
    float s = 0.f;
    for (int i = tid; i < np; i += 256) s += partial[i];
    red[tid] = s;
    __syncthreads();
    for (int o = 128; o > 0; o >>= 1) {
        if (tid < o) red[tid] += red[tid + o];
        __syncthreads();
    }
    float th = 1.f / (1.f + expf(-red[0] * inv_n));
    __syncthreads();
    return th;
}

// ---------------------------------------------------------------------------
// last-block pattern: write partial -> fence -> ticket; unique winner returns
// true (all peers' partials and weight-reads complete at that point).
// ---------------------------------------------------------------------------
__device__ __forceinline__ bool last_block(unsigned int* cnt, unsigned int total, int tid)
{
    __shared__ unsigned int tk;
    __threadfence();
    if (tid == 0) tk = atomicAdd(cnt, 1u);
    __syncthreads();
    if (tk != total - 1) return false;
    __threadfence();
    return true;
}

// ---------------------------------------------------------------------------
// Coalesced bf16 tile write via LDS staging (proven round 4). Row-major.
// ---------------------------------------------------------------------------
template<int BM, int BN, int FM, int FN>
__device__ __forceinline__ void write_tile(char* lds, f32x4 (&a)[FM][FN],
                                           __hip_bfloat16* __restrict__ C,
                                           long base, int N, int tid)
{
    const int wave = tid >> 6;
    const int lane = tid & 63;
    const int wm = wave >> 1, wn = wave & 1;
    const int lc = lane & 15;
    const int lr4 = (lane >> 4) << 2;
    __syncthreads();
    #pragma unroll
    for (int j = 0; j < FN; ++j) {
        int colb = (wn * (FN * 16) + j * 16 + lc) * 2;
        #pragma unroll
        for (int i = 0; i < FM; ++i) {
            int row0 = wm * (FM * 16) + i * 16 + lr4;
            #pragma unroll
            for (int r = 0; r < 4; ++r) {
                int row = row0 + r;
                *reinterpret_cast<unsigned short*>(
                    lds + row * (BN * 2) + (colb ^ (((row >> 2) & 3) << 5))) =
                    f2bfu(a[i][j][r]);
            }
        }
    }
    __syncthreads();
    const int TPR = BN / 8;
    const int RPP = 256 / TPR;
    #pragma unroll
    for (int p = 0; p < BM / RPP; ++p) {
        int row = p * RPP + tid / TPR;
        int cb = (tid % TPR) * 16;
        int pb = cb ^ (((row >> 2) & 3) << 5);
        uint4 v = *reinterpret_cast<const uint4*>(lds + row * (BN * 2) + pb);
        *reinterpret_cast<uint4*>(reinterpret_cast<char*>(C + base + (long)row * N) + cb) = v;
    }
}

// ---------------------------------------------------------------------------
// Transposed tile write (proven round 11).
// ---------------------------------------------------------------------------
template<int BM, int BN, int FM, int FN>
__device__ __forceinline__ void write_tileT(char* lds, f32x4 (&a)[FM][FN],
                                            __hip_bfloat16* __restrict__ CT,
                                            long baseT, int ldT, int tid)
{
    const int wave = tid >> 6;
    const int lane = tid & 63;
    const int wm = wave >> 1, wn = wave & 1;
    const int lc = lane & 15;
    const int lr4 = (lane >> 4) << 2;
    __syncthreads();
    #pragma unroll
    for (int j = 0; j < FN; ++j) {
        int c = wn * (FN * 16) + j * 16 + lc;
        int cbase = c * (BM * 2);
        int swz = ((c >> 2) & 3) << 5;
        #pragma unroll
        for (int i = 0; i < FM; ++i) {
            int m0 = wm * (FM * 16) + i * 16 + lr4;
            #pragma unroll
            for (int r = 0; r < 4; ++r) {
                int m = m0 + r;
                *reinterpret_cast<unsigned short*>(lds + cbase + ((m * 2) ^ swz)) =
                    f2bfu(a[i][j][r]);
            }
        }
    }
    __syncthreads();
    const int TPR = BM / 8;
    const int RPP = 256 / TPR;
    #pragma unroll
    for (int p = 0; p < BN / RPP; ++p) {
        int c = p * RPP + tid / TPR;
        int tb = (tid % TPR) * 16;
        int pb = tb ^ (((c >> 2) & 3) << 5);
        uint4 v = *reinterpret_cast<const uint4*>(lds + c * (BM * 2) + pb);
        *reinterpret_cast<uint4*>(reinterpret_cast<char*>(CT + baseT + (long)c * ldT) + tb) = v;
    }
}

// ---------------------------------------------------------------------------
// staging of one K=64 slab of A(BM rows) + B(BN rows) into swizzled LDS
// ---------------------------------------------------------------------------
template<int BM, int BN>
__device__ __forceinline__ void stage_tiles(const __hip_bfloat16* __restrict__ Ab,
                                            const __hip_bfloat16* __restrict__ Bb,
                                            char* AsB, char* BsB,
                                            int m0, int n0, int k0, int KA, int KB,
                                            int wave, int lane)
{
    const int NCH = (BM + BN) / 32;
    const int lr = lane >> 3;
    const int ls = lane & 7;
    #pragma unroll
    for (int cc = 0; cc < NCH; ++cc) {
        int c = wave * NCH + cc;
        const __hip_bfloat16* src;
        char* ldsb;
        if (c < BM / 8) {
            int r = c * 8 + lr;
            ldsb = AsB + c * 1024;
            src = Ab + ((long)(m0 + r) * KA + k0 + ((ls ^ (r & 7)) << 3));
        } else {
            int c2 = c - BM / 8;
            int r = c2 * 8 + lr;
            ldsb = BsB + c2 * 1024;
            src = Bb + ((long)(n0 + r) * KB + k0 + ((ls ^ (r & 7)) << 3));
        }
        __builtin_amdgcn_global_load_lds(GLP(src), LDSP(ldsb), 16, 0, 0);
    }
}

template<int BM, int BN, int FM, int FN>
__device__ __forceinline__ void mfma_tiles(char* AsB, char* BsB,
                                           f32x4 (&acc)[FM][FN], int wave, int lane)
{
    const int wm = wave >> 1, wn = wave & 1;
    #pragma unroll
    for (int ksl = 0; ksl < 2; ++ksl) {
        bf16x8 af[FM], bfr[FN];
        #pragma unroll
        for (int i = 0; i < FM; ++i) {
            int row = wm * (FM * 16) + i * 16 + (lane & 15);
            int off = (ksl * 64 + ((lane >> 4) << 4)) ^ ((row & 7) << 4);
            af[i] = *reinterpret_cast<const bf16x8*>(AsB + row * 128 + off);
        }
        #pragma unroll
        for (int j = 0; j < FN; ++j) {
            int row = wn * (FN * 16) + j * 16 + (lane & 15);
            int off = (ksl * 64 + ((lane >> 4) << 4)) ^ ((row & 7) << 4);
            bfr[j] = *reinterpret_cast<const bf16x8*>(BsB + row * 128 + off);
        }
        #pragma unroll
        for (int i = 0; i < FM; ++i)
            #pragma unroll
            for (int j = 0; j < FN; ++j)
                acc[i][j] = __builtin_amdgcn_mfma_f32_16x16x32_bf16(
                    af[i], bfr[j], acc[i][j], 0, 0, 0);
    }
}

// ---------------------------------------------------------------------------
// Pipelined multi-step runner (round-13 proven: __syncthreads only).
// ---------------------------------------------------------------------------
template<int BM, int BN, int FM, int FN, int NS, int NA>
__device__ __forceinline__ void pipe_run(
    const __hip_bfloat16* const (&sA)[NS], const __hip_bfloat16* const (&sB)[NS],
    const int (&sK)[NS], const int (&sk0)[NS],
    char* buf0, char* buf1,
    f32x4 (&acc0)[FM][FN], f32x4 (&acc1)[FM][FN],
    int m0, int n0, int wave, int lane)
{
    constexpr int BOFF = BM * 128;
    stage_tiles<BM, BN>(sA[0], sB[0], buf0, buf0 + BOFF, m0, n0, sk0[0],
                        sK[0], sK[0], wave, lane);
    __syncthreads();
    #pragma unroll
    for (int t = 0; t < NS; ++t) {
        char* bc = (t & 1) ? buf1 : buf0;
        if (t + 1 < NS) {
            char* bn = (t & 1) ? buf0 : buf1;
            stage_tiles<BM, BN>(sA[t + 1], sB[t + 1], bn, bn + BOFF, m0, n0,
                                sk0[t + 1], sK[t + 1], sK[t + 1], wave, lane);
        }
        if (t < NA) mfma_tiles<BM, BN, FM, FN>(bc, bc + BOFF, acc0, wave, lane);
        else        mfma_tiles<BM, BN, FM, FN>(bc, bc + BOFF, acc1, wave, lane);
        __syncthreads();
    }
}

// ---------------------------------------------------------------------------
// transpose-convert fp32 (R,C) -> bf16 (C,R), optional per-src-row scale + sign
// ---------------------------------------------------------------------------
__device__ __forceinline__ void tcvt_body(const float* __restrict__ in,
                                          unsigned short* __restrict__ out,
                                          const float* cs, float us,
                                          int R, int C, int r0, int c0)
{
    __shared__ float t[64][65];
    int tr = threadIdx.x >> 6;
    int tc = threadIdx.x & 63;
    #pragma unroll
    for (int i = 0; i < 16; ++i) {
        int r = i * 4 + tr;
        t[r][tc] = in[(long)(r0 + r) * C + c0 + tc];
    }
    __syncthreads();
    float sc = (cs ? cs[r0 + tc] : 1.0f) * us;
    #pragma unroll
    for (int i = 0; i < 16; ++i) {
        int r = i * 4 + tr;
        out[(long)(c0 + r) * R + r0 + tc] = f2bfu(t[tc][r] * sc);
    }
}

// coeff recompute (per block, 256 threads)
__device__ __forceinline__ void coeff_local(const float* lg, const float* gb,
                                            const float* Wn, float* cof, int t)
{
    float l0 = lg[0] + gb[t * 3 + 0];
    float l1 = lg[1] + gb[t * 3 + 1];
    float l2 = lg[2] + gb[t * 3 + 2];
    int bl = 0;
    float bv = l0;
    if (l1 > bv) { bv = l1; bl = 1; }
    if (l2 > bv) { bv = l2; bl = 2; }
    float s = 0.f;
    #pragma unroll
    for (int q = 0; q < 8; ++q) s += Wn[t * 8 + q] * PAT[bl][q];
    cof[t] = s;
}

struct WTArgs {
    const float* src[8];
    unsigned short* dst[8];
    int ci[8];
    float sgn[8];
    int R[8], C[8];
};
struct WFArgs {
    const float* Wsrc[4];
    const float* Wbig[4];
    int ci[4], incl[4], N[4];
    unsigned short* dst[4];
};
struct FVArgs {
    const float* W[6];
    int ci[6];
    const float* v[6];
    const float* base[6];
    float* out[6];
    int K[6], N[6];
};
struct PrepArgs {
    const float *logits0, *gumb0, *Wnl0, *logits1, *gumb1, *Wnl1;
    const float* adj;
    unsigned int* adjb;
    float* ars;
    const float* x;
    unsigned short *xbf, *xT;
    unsigned int* cnt;
};

// ---------------------------------------------------------------------------
// prep_k: ONE launch: counters | adj cvt+rowsum (512) | x cvt+T (1024) |
// weight transposes (128) | weight folds (256) | vector folds (256)
// coeff vectors recomputed locally by blocks that need them.
// ---------------------------------------------------------------------------
__global__ __launch_bounds__(256) void prep_k(PrepArgs p, WTArgs wa, WFArgs wf, FVArgs fv)
{
    __shared__ float cofA[256];
    __shared__ float cofB[256];
    __shared__ float redu[256];
    const int b = blockIdx.x;
    const int t = threadIdx.x;
    if (b == 0 && t < 4) p.cnt[t] = 0;
    if (b < NN) {
        float2 v = reinterpret_cast<const float2*>(p.adj)[b * 256 + t];
        p.adjb[b * 256 + t] = (unsigned int)f2bfu(v.x) | ((unsigned int)f2bfu(v.y) << 16);
        redu[t] = v.x + v.y;
        __syncthreads();
        for (int o = 128; o > 0; o >>= 1) {
            if (t < o) redu[t] += redu[t + o];
            __syncthreads();
        }
        if (t == 0) p.ars[b] = redu[0];
    } else if (b < NN + 8 * BB) {
        __shared__ float tl[64][65];
        int tt = b - NN;
        int bz = tt >> 3;
        int r0 = (tt & 7) * 64;
        const long base = (long)bz * NN * DIN;
        const int tr4 = t >> 6;
        const int tc  = t & 63;
        #pragma unroll
        for (int i = 0; i < 16; ++i) {
            int r = i * 4 + tr4;
            float v = p.x[base + (long)(r0 + r) * DIN + tc];
            tl[r][tc] = v;
            p.xbf[base + (long)(r0 + r) * DIN + tc] = f2bfu(v);
        }
        __syncthreads();
        #pragma unroll
        for (int i = 0; i < 16; ++i) {
            int d = i * 4 + tr4;
            p.xT[base + (long)d * NN + r0 + tc] = f2bfu(tl[tc][d]);
        }
    } else if (b < NN + 8 * BB + 128) {
        int xg = b - NN - 8 * BB;
        int wgt = xg >> 4;
        int tl2 = xg & 15;
        int R = wa.R[wgt], C = wa.C[wgt];
        int tilesX = C >> 6;
        int tiles = (R >> 6) * tilesX;
        if (tl2 >= tiles) return;
        const float* cs = nullptr;
        if (wa.ci[wgt]) {
            if (wa.ci[wgt] == 1) coeff_local(p.logits0, p.gumb0, p.Wnl0, cofA, t);
            else                 coeff_local(p.logits1, p.gumb1, p.Wnl1, cofA, t);
            __syncthreads();
            cs = cofA;
        }
        tcvt_body(wa.src[wgt], wa.dst[wgt], cs, wa.sgn[wgt], R, C,
                  (tl2 / tilesX) * 64, (tl2 % tilesX) * 64);
    } else if (b < NN + 8 * BB + 128 + 256) {
        int xg = b - NN - 8 * BB - 128;
        int cs = xg >> 6;
        int m = xg & 63;
        float cv = 1.0f;
        if (wf.ci[cs]) {
            if (wf.ci[cs] == 1) coeff_local(p.logits0, p.gumb0, p.Wnl0, cofA, t);
            else                coeff_local(p.logits1, p.gumb1, p.Wnl1, cofA, t);
            __syncthreads();
            cv = cofA[t];
        }
        cofB[t] = wf.Wsrc[cs][m * 256 + t] * cv;
        __syncthreads();
        int n = t;
        int N = wf.N[cs];
        if (n >= N) return;
        float s = wf.incl[cs] ? wf.Wsrc[cs][m * 256 + n] : 0.f;
        const float* Wb = wf.Wbig[cs];
        #pragma unroll 8
        for (int k = 0; k < 256; ++k)
            s += cofB[k] * Wb[(long)k * N + n];
        wf.dst[cs][n * 64 + m] = f2bfu(s);
    } else {
        int n = b - (NN + 8 * BB + 128 + 256);
        coeff_local(p.logits0, p.gumb0, p.Wnl0, cofA, t);
        coeff_local(p.logits1, p.gumb1, p.Wnl1, cofB, t);
        __syncthreads();
        for (int cs = 0; cs < 6; ++cs) {
            __syncthreads();
            if (n >= fv.N[cs]) continue;
            float s = 0.f;
            if (t < fv.K[cs]) {
                float cc = (fv.ci[cs] == 1) ? cofA[t] : (fv.ci[cs] == 2 ? cofB[t] : 1.0f);
                s = fv.v[cs][t] * cc * fv.W[cs][(long)t * fv.N[cs] + n];
            }
            redu[t] = s;
            __syncthreads();
            for (int o = 128; o > 0; o >>= 1) {
                if (t < o) redu[t] += redu[t + o];
                __syncthreads();
            }
            if (t == 0)
                fv.out[cs][n] = (fv.base[cs] ? fv.base[cs][n] : 0.f) + redu[0];
        }
    }
}

// ---------------------------------------------------------------------------
// Rbf producer: C = A@B + bias, row-major AND per-batch transposed.
// ---------------------------------------------------------------------------
template<int BM, int BN, int FM, int FN>
__global__ __launch_bounds__(256) void gemm_res_k(
    const __hip_bfloat16* __restrict__ A, const __hip_bfloat16* __restrict__ Bt,
    const float* __restrict__ bias,
    __hip_bfloat16* __restrict__ Cb, __hip_bfloat16* __restrict__ CbT,
    int M, int N, int K)
{
    __shared__ __attribute__((aligned(128))) char lds[(BM + BN) * 128];
    char* AsB = lds;
    char* BsB = lds + BM * 128;

    const int m0 = blockIdx.y * BM;
    const int tid  = threadIdx.x;
    const int wave = tid >> 6;
    const int lane = tid & 63;
    const int wn = wave & 1;

    f32x4 acc[FM][FN];
    #pragma unroll
    for (int i = 0; i < FM; ++i)
        #pragma unroll
        for (int j = 0; j < FN; ++j)
            acc[i][j] = (f32x4){0.f, 0.f, 0.f, 0.f};

    for (int k0 = 0; k0 < K; k0 += 64) {
        stage_tiles<BM, BN>(A, Bt, AsB, BsB, m0, 0, k0, K, K, wave, lane);
        __syncthreads();
        mfma_tiles<BM, BN, FM, FN>(AsB, BsB, acc, wave, lane);
        __syncthreads();
    }

    const int lc = lane & 15;
    #pragma unroll
    for (int j = 0; j < FN; ++j) {
        float bv = bias[wn * (FN * 16) + j * 16 + lc];
        #pragma unroll
        for (int i = 0; i < FM; ++i)
            #pragma unroll
            for (int r = 0; r < 4; ++r)
                acc[i][j][r] += bv;
    }
    write_tile<BM, BN, FM, FN>(lds, acc, Cb, (long)m0 * N, N, tid);
    long baseT = (long)(m0 / NN) * ((long)N * NN) + (m0 % NN);
    write_tileT<BM, BN, FM, FN>(lds, acc, CbT, baseT, NN, tid);
}

// ---------------------------------------------------------------------------
// t0radj_k: fused adj@[x | Rbf] — shared A staging, two accumulators (rd 14).
// ---------------------------------------------------------------------------
__global__ __launch_bounds__(256) void t0radj_k(
    const __hip_bfloat16* __restrict__ adjb,
    const __hip_bfloat16* __restrict__ xT,
    const __hip_bfloat16* __restrict__ RbfT,
    __hip_bfloat16* __restrict__ T0,
    __hip_bfloat16* __restrict__ Radj)
{
    constexpr int BM = 128, BN = 64;
    constexpr int ABYTES = BM * 128;
    constexpr int BBYTES = BN * 128;
    constexpr int BUF = ABYTES + 2 * BBYTES;
    __shared__ __attribute__((aligned(128))) char lds[2 * BUF];

    const int d   = blockIdx.x;
    const int xcd = d & 7;
    const int q   = d >> 3;
    const int t   = q & 3;
    const int bz  = xcd + ((q >> 2) << 3);
    const int m0  = t * BM;

    const __hip_bfloat16* B1 = xT + (long)bz * (64L * NN);
    const __hip_bfloat16* B2 = RbfT + (long)bz * (64L * NN);

    const int tid  = threadIdx.x;
    const int wave = tid >> 6;
    const int lane = tid & 63;
    const int lr = lane >> 3;
    const int ls = lane & 7;

    f32x4 accA[4][2], accB[4][2];
    #pragma unroll
    for (int i = 0; i < 4; ++i)
        #pragma unroll
        for (int j = 0; j < 2; ++j) {
            accA[i][j] = (f32x4){0.f, 0.f, 0.f, 0.f};
            accB[i][j] = (f32x4){0.f, 0.f, 0.f, 0.f};
        }

    auto stage2 = [&](char* buf, int k0) {
        #pragma unroll
        for (int cc = 0; cc < 8; ++cc) {
            int c = wave * 8 + cc;
            const __hip_bfloat16* src;
            char* ldsb;
            if (c < 16) {
                int r = c * 8 + lr;
                ldsb = buf + c * 1024;
                src = adjb + ((long)(m0 + r) * NN + k0 + ((ls ^ (r & 7)) << 3));
            } else if (c < 24) {
                int r = (c - 16) * 8 + lr;
                ldsb = buf + ABYTES + (c - 16) * 1024;
                src = B1 + ((long)r * NN + k0 + ((ls ^ (r & 7)) << 3));
            } else {
                int r = (c - 24) * 8 + lr;
                ldsb = buf + ABYTES + BBYTES + (c - 24) * 1024;
                src = B2 + ((long)r * NN + k0 + ((ls ^ (r & 7)) << 3));
            }
            __builtin_amdgcn_global_load_lds(GLP(src), LDSP(ldsb), 16, 0, 0);
        }
    };

    stage2(lds, 0);
    __syncthreads();
    #pragma unroll
    for (int s = 0; s < 8; ++s) {
        char* bc = lds + (s & 1) * BUF;
        if (s + 1 < 8) stage2(lds + ((s + 1) & 1) * BUF, (s + 1) * 64);
        mfma_tiles<BM, BN, 4, 2>(bc, bc + ABYTES, accA, wave, lane);
        mfma_tiles<BM, BN, 4, 2>(bc, bc + ABYTES + BBYTES, accB, wave, lane);
        __syncthreads();
    }

    long base = (long)bz * ((long)NN * BN) + (long)m0 * BN;
    write_tile<BM, BN, 4, 2>(lds, accA, T0, base, BN, tid);
    write_tile<BM, BN, 4, 2>(lds, accB, Radj, base, BN, tid);
}

// ---------------------------------------------------------------------------
// Batched pipelined GEMM with XCD-grouped block swizzle (round 13).
// ---------------------------------------------------------------------------
template<int BM, int BN, int FM, int FN, int GX, int NB, int NS>
__global__ __launch_bounds__(256) void gemm_bt_swz_k(
    const __hip_bfloat16* __restrict__ A, const __hip_bfloat16* __restrict__ Bt,
    __hip_bfloat16* __restrict__ Cb,
    int M, int N, int K, long sA, long sB, long sC)
{
    __shared__ __attribute__((aligned(128))) char lds[2 * (BM + BN) * 128];

    const int d   = blockIdx.x;
    const int xcd = d & 7;
    const int q   = d >> 3;
    const int t   = q % NB;
    const int bz  = xcd + ((q / NB) << 3);
    const int n0  = (t % GX) * BN;
    const int m0  = (t / GX) * BM;

    const __hip_bfloat16* Ab = A + (long)bz * sA;
    const __hip_bfloat16* Bb = Bt + (long)bz * sB;

    const int tid  = threadIdx.x;
    const int wave = tid >> 6;
    const int lane = tid & 63;

    f32x4 acc[FM][FN];
    #pragma unroll
    for (int i = 0; i < FM; ++i)
        #pragma unroll
        for (int j = 0; j < FN; ++j)
            acc[i][j] = (f32x4){0.f, 0.f, 0.f, 0.f};

    const __hip_bfloat16* pA[NS];
    const __hip_bfloat16* pB[NS];
    int pK[NS], pk0[NS];
    #pragma unroll
    for (int s = 0; s < NS; ++s) { pA[s] = Ab; pB[s] = Bb; pK[s] = K; pk0[s] = s * 64; }

    pipe_run<BM, BN, FM, FN, NS, NS>(pA, pB, pK, pk0,
                                     lds, lds + (BM + BN) * 128,
                                     acc, acc, m0, n0, wave, lane);

    write_tile<BM, BN, FM, FN>(lds, acc, Cb, (long)bz * sC + (long)m0 * N + n0, N, tid);
}

// ---------------------------------------------------------------------------
// dual1_k (D0) + sc0 last-block epilogue.
// ---------------------------------------------------------------------------
template<int BM, int BN, int FM, int FN>
__global__ __launch_bounds__(256) void dual1_k(
    const __hip_bfloat16* __restrict__ A0, const __hip_bfloat16* __restrict__ B0, int K0,
    const __hip_bfloat16* __restrict__ A1, const __hip_bfloat16* __restrict__ B1, int K1,
    const float* __restrict__ b1, const float* __restrict__ b2,
    float* __restrict__ partial, int M, int N,
    unsigned int* cnt, float inv_n,
    unsigned short* Wg0pT, unsigned short* Wrg0pT,
    const float* __restrict__ bg0p, const float* __restrict__ brg0p,
    const float* __restrict__ crow0, float* __restrict__ cv0)
{
    __shared__ __attribute__((aligned(128))) char lds[2 * (BM + BN) * 128];

    const int d   = blockIdx.x;
    const int q   = d >> 3;
    const int nx  = q & 1;
    const int my  = (d & 7) + ((q >> 1) << 3);
    const int m0  = my * BM;
    const int n0  = nx * BN;

    const int tid  = threadIdx.x;
    const int wave = tid >> 6;
    const int lane = tid & 63;
    const int wn = wave & 1;

    f32x4 acc[FM][FN];
    #pragma unroll
    for (int i = 0; i < FM; ++i)
        #pragma unroll
        for (int j = 0; j < FN; ++j)
            acc[i][j] = (f32x4){0.f, 0.f, 0.f, 0.f};

    const __hip_bfloat16* pA[2] = {A0, A1};
    const __hip_bfloat16* pB[2] = {B0, B1};
    int pK[2] = {K0, K1};
    int pk0[2] = {0, 0};
    pipe_run<BM, BN, FM, FN, 2, 2>(pA, pB, pK, pk0,
                                   lds, lds + (BM + BN) * 128,
                                   acc, acc, m0, n0, wave, lane);

    const int lc = lane & 15;
    float dsum = 0.f;
    #pragma unroll
    for (int j = 0; j < FN; ++j) {
        int col = n0 + wn * (FN * 16) + j * 16 + lc;
        float bd = b1[col] - b2[col];
        #pragma unroll
        for (int i = 0; i < FM; ++i)
            #pragma unroll
            for (int r = 0; r < 4; ++r) {
                float dd = acc[i][j][r] + bd;
                dsum += dd * dd;
            }
    }

    float* red = (float*)lds;
    red[tid] = dsum;
    __syncthreads();
    for (int o = 128; o > 0; o >>= 1) {
        if (tid < o) red[tid] += red[tid + o];
        __syncthreads();
    }
    if (tid == 0) partial[my * 2 + nx] = red[0];

    if (!last_block(cnt, 2048u, tid)) return;
    // sc0: th0/om0 scale folded weights; build cv0
    float th = block_th(partial, 2048, inv_n, red, tid);
    float om = 1.f - th;
    for (int g = tid; g < 16384; g += 256) {
        Wg0pT[g] = f2bfu(th * bf2f(Wg0pT[g]));
        Wrg0pT[g] = f2bfu(om * bf2f(Wrg0pT[g]));
    }
    cv0[tid] = th * bg0p[tid] + om * brg0p[tid] + crow0[tid];
}

// ---------------------------------------------------------------------------
// wave2T_k (W0) + sc1 last-block epilogue.
// ---------------------------------------------------------------------------
template<int BM, int BN, int FM, int FN>
__global__ __launch_bounds__(256) void wave2T_k(
    const __hip_bfloat16* __restrict__ A0, const __hip_bfloat16* __restrict__ B0, int K0,
    const __hip_bfloat16* __restrict__ A1, const __hip_bfloat16* __restrict__ B1, int K1,
    const __hip_bfloat16* __restrict__ A2, const __hip_bfloat16* __restrict__ B2, int K2,
    const float* __restrict__ cv, const float* __restrict__ b2v,
    __hip_bfloat16* __restrict__ C1T, float* __restrict__ partial_out, int M, int N,
    unsigned int* cnt, float inv_n,
    unsigned short* Wg1T, const unsigned short* Wrw0T, unsigned short* Wrg0pT,
    unsigned short* WcombT, unsigned short* Wg0pT, unsigned short* WrwWg1T,
    const float* __restrict__ bg1, const float* __restrict__ brw0,
    const float* __restrict__ cv0, const float* __restrict__ bw1v,
    float* __restrict__ bv1g, float* __restrict__ bw1s)
{
    __shared__ __attribute__((aligned(128))) char lds[2 * (BM + BN) * 128];

    const int d   = blockIdx.x;
    const int q   = d >> 3;
    const int nx  = q & 1;
    const int my  = (d & 7) + ((q >> 1) << 3);
    const int m0  = my * BM;
    const int n0  = nx * BN;

    const int tid  = threadIdx.x;
    const int wave = tid >> 6;
    const int lane = tid & 63;
    const int wn = wave & 1;

    f32x4 acc0[FM][FN], acc1[FM][FN];
    #pragma unroll
    for (int i = 0; i < FM; ++i)
        #pragma unroll
        for (int j = 0; j < FN; ++j) {
            acc0[i][j] = (f32x4){0.f, 0.f, 0.f, 0.f};
            acc1[i][j] = (f32x4){0.f, 0.f, 0.f, 0.f};
        }

    const __hip_bfloat16* pA[3] = {A0, A1, A2};
    const __hip_bfloat16* pB[3] = {B0, B1, B2};
    int pK[3] = {K0, K1, K2};
    int pk0[3] = {0, 0, 0};
    pipe_run<BM, BN, FM, FN, 3, 2>(pA, pB, pK, pk0,
                                   lds, lds + (BM + BN) * 128,
                                   acc0, acc1, m0, n0, wave, lane);

    const int lc = lane & 15;
    float dsum = 0.f;
    #pragma unroll
    for (int j = 0; j < FN; ++j) {
        int col = n0 + wn * (FN * 16) + j * 16 + lc;
        float c1 = cv[col];
        float c2 = b2v[col];
        #pragma unroll
        for (int i = 0; i < FM; ++i)
            #pragma unroll
            for (int r = 0; r < 4; ++r) {
                float v1 = acc0[i][j][r] + c1;
                float v2 = acc1[i][j][r] + c2;
                acc0[i][j][r] = v1;
                float dd = v1 - v2;
                dsum += dd * dd;
            }
    }

    float* red = (float*)lds;
    red[tid] = dsum;
    __syncthreads();
    for (int o = 128; o > 0; o >>= 1) {
        if (tid < o) red[tid] += red[tid + o];
        __syncthreads();
    }
    if (tid == 0) partial_out[my * 2 + nx] = red[0];

    long baseT = (long)(m0 / NN) * ((long)N * NN) + (long)n0 * NN + (m0 % NN);
    write_tileT<BM, BN, FM, FN>(lds, acc0, C1T, baseT, NN, tid);

    if (!last_block(cnt, 2048u, tid)) return;
    // sc1
    float th = block_th(partial_out, 2048, inv_n, red, tid);
    float om = 1.f - th;
    for (int g = tid; g < 65536; g += 256)
        Wg1T[g] = f2bfu(th * bf2f(Wg1T[g]));
    for (int g = tid; g < 16384; g += 256) {
        WcombT[g]  = f2bfu(th * bf2f(Wrg0pT[g]) + om * bf2f(Wrw0T[g]));
        Wg0pT[g]   = f2bfu(th * bf2f(Wg0pT[g]));
        WrwWg1T[g] = f2bfu(om * bf2f(WrwWg1T[g]));
    }
    bv1g[tid] = bg1[tid] + om * brw0[tid] + th * cv0[tid];
    bw1s[tid] = om * bw1v[tid];
}

// ---------------------------------------------------------------------------
// gmix5_k + sc2 last-block epilogue.
// ---------------------------------------------------------------------------
template<int BM, int BN, int FM, int FN>
__global__ __launch_bounds__(256) void gmix5_k(
    const __hip_bfloat16* __restrict__ A0, const __hip_bfloat16* __restrict__ B0, int K0,
    const __hip_bfloat16* __restrict__ A1, const __hip_bfloat16* __restrict__ B1, int K1,
    const __hip_bfloat16* __restrict__ A2, const __hip_bfloat16* __restrict__ B2, int K2,
    const __hip_bfloat16* __restrict__ A3, const __hip_bfloat16* __restrict__ B3, int K3,
    const __hip_bfloat16* __restrict__ A4, const __hip_bfloat16* __restrict__ B4, int K4,
    const float* __restrict__ bv1, const float* __restrict__ b2v,
    const float* __restrict__ ars, const float* __restrict__ bw1s,
    __hip_bfloat16* __restrict__ C1, float* __restrict__ partial_out, int M, int N,
    unsigned int* cnt, float inv_n,
    unsigned short* Wc1T, unsigned short* Wrgc1T,
    const float* __restrict__ brgc1, const float* __restrict__ crow1,
    float* __restrict__ cv2)
{
    __shared__ __attribute__((aligned(128))) char lds[2 * (BM + BN) * 128];

    const int d  = blockIdx.x;
    const int q  = d >> 3;
    const int nx = q & 1;
    const int my = (d & 7) + ((q >> 1) << 3);
    const int m0 = my * BM;
    const int n0 = nx * BN;

    const int tid  = threadIdx.x;
    const int wave = tid >> 6;
    const int lane = tid & 63;
    const int wm = wave >> 1, wn = wave & 1;

    f32x4 acc0[FM][FN], acc1[FM][FN];
    #pragma unroll
    for (int i = 0; i < FM; ++i)
        #pragma unroll
        for (int j = 0; j < FN; ++j) {
            acc0[i][j] = (f32x4){0.f, 0.f, 0.f, 0.f};
            acc1[i][j] = (f32x4){0.f, 0.f, 0.f, 0.f};
        }

    const __hip_bfloat16* pA[8] = {A0, A0, A0, A0, A1, A2, A3, A4};
    const __hip_bfloat16* pB[8] = {B0, B0, B0, B0, B1, B2, B3, B4};
    int pK[8]  = {K0, K0, K0, K0, K1, K2, K3, K4};
    int pk0[8] = {0, 64, 128, 192, 0, 0, 0, 0};
    pipe_run<BM, BN, FM, FN, 8, 7>(pA, pB, pK, pk0,
                                   lds, lds + (BM + BN) * 128,
                                   acc0, acc1, m0, n0, wave, lane);

    const int lc  = lane & 15;
    const int lr4 = (lane >> 4) << 2;
    const int node0 = m0 & (NN - 1);
    float dsum = 0.f;
    #pragma unroll
    for (int j = 0; j < FN; ++j) {
        int col = n0 + wn * (FN * 16) + j * 16 + lc;
        float c1 = bv1[col];
        float c2 = b2v[col];
        float bw = bw1s[col];
        #pragma unroll
        for (int i = 0; i < FM; ++i) {
            int rowl = wm * (FM * 16) + i * 16 + lr4;
            #pragma unroll
            for (int r = 0; r < 4; ++r) {
                float av = ars[node0 + rowl + r];
                float v1 = acc0[i][j][r] + c1 + av * bw;
                float v2 = acc1[i][j][r] + c2;
                acc0[i][j][r] = v1;
                float dd = v1 - v2;
                dsum += dd * dd;
            }
        }
    }

    float* red = (float*)lds;
    red[tid] = dsum;
    __syncthreads();
    for (int o = 128; o > 0; o >>= 1) {
        if (tid < o) red[tid] += red[tid + o];
        __syncthreads();
    }
    if (tid == 0) partial_out[my * 2 + nx] = red[0];

    write_tile<BM, BN, FM, FN>(lds, acc0, C1, (long)m0 * N + n0, N, tid);

    if (!last_block(cnt, 2048u, tid)) return;
    // sc2
    float th = block_th(partial_out, 2048, inv_n, red, tid);
    float om = 1.f - th;
    for (int g = tid; g < 16384; g += 256)
        Wc1T[g] = f2bfu(th * bf2f(Wc1T[g]));
    for (int g = tid; g < 4096; g += 256)
        Wrgc1T[g] = f2bfu(om * bf2f(Wrgc1T[g]));
    if (tid < 64) cv2[tid] = om * brgc1[tid] + crow1[tid];
}

// ---------------------------------------------------------------------------
// wave2_k (F): 6 pipelined steps (5 -> acc0, 1 -> acc1), plain grid.
// ---------------------------------------------------------------------------
template<int BM, int BN, int FM, int FN>
__global__ __launch_bounds__(256) void wave2_k(
    const __hip_bfloat16* __restrict__ A0, const __hip_bfloat16* __restrict__ B0, int K0,
    const __hip_bfloat16* __restrict__ A1, const __hip_bfloat16* __restrict__ B1, int K1,
    const __hip_bfloat16* __restrict__ A2, const __hip_bfloat16* __restrict__ B2, int K2,
    const float* __restrict__ cv, const float* __restrict__ b2v,
    __hip_bfloat16* __restrict__ C1, __hip_bfloat16* __restrict__ C2,
    float* __restrict__ partial_out, int M, int N)
{
    __shared__ __attribute__((aligned(128))) char lds[2 * (BM + BN) * 128];

    const int m0 = blockIdx.y * BM;
    const int n0 = blockIdx.x * BN;
    const int pidx = blockIdx.y * gridDim.x + blockIdx.x;

    const int tid  = threadIdx.x;
    const int wave = tid >> 6;
    const int lane = tid & 63;
    const int wn = wave & 1;

    f32x4 acc0[FM][FN], acc1[FM][FN];
    #pragma unroll
    for (int i = 0; i < FM; ++i)
        #pragma unroll
        for (int j = 0; j < FN; ++j) {
            acc0[i][j] = (f32x4){0.f, 0.f, 0.f, 0.f};
            acc1[i][j] = (f32x4){0.f, 0.f, 0.f, 0.f};
        }

    const __hip_bfloat16* pA[6] = {A0, A0, A0, A0, A1, A2};
    const __hip_bfloat16* pB[6] = {B0, B0, B0, B0, B1, B2};
    int pK[6]  = {K0, K0, K0, K0, K1, K2};
    int pk0[6] = {0, 64, 128, 192, 0, 0};
    pipe_run<BM, BN, FM, FN, 6, 5>(pA, pB, pK, pk0,
                                   lds, lds + (BM + BN) * 128,
                                   acc0, acc1, m0, n0, wave, lane);

    const int lc = lane & 15;
    float dsum = 0.f;
    #pragma unroll
    for (int j = 0; j < FN; ++j) {
        int col = n0 + wn * (FN * 16) + j * 16 + lc;
        float c1 = cv[col];
        float c2 = b2v[col];
        #pragma unroll
        for (int i = 0; i < FM; ++i)
            #pragma unroll
            for (int r = 0; r < 4; ++r) {
                float v1 = acc0[i][j][r] + c1;
                float v2 = acc1[i][j][r] + c2;
                acc0[i][j][r] = v1;
                acc1[i][j][r] = v2;
                float dd = v1 - v2;
                dsum += dd * dd;
            }
    }

    float* red = (float*)lds;
    red[tid] = dsum;
    __syncthreads();
    for (int o = 128; o > 0; o >>= 1) {
        if (tid < o) red[tid] += red[tid + o];
        __syncthreads();
    }
    if (tid == 0) partial_out[pidx] = red[0];

    write_tile<BM, BN, FM, FN>(lds, acc0, C1, (long)m0 * N + n0, N, tid);
    write_tile<BM, BN, FM, FN>(lds, acc1, C2, (long)m0 * N + n0, N, tid);
}

// ---------------------------------------------------------------------------
// final mix (th in-kernel): out = th*h + (1-th)*r, fp32 out
// ---------------------------------------------------------------------------
__global__ __launch_bounds__(256) void mixfinal_k(
    const unsigned short* __restrict__ h, const unsigned short* __restrict__ r,
    const float* __restrict__ partial_in, int np_in, float inv_in,
    float* __restrict__ out, long n4)
{
    __shared__ float sm[256];
    const float th = block_th(partial_in, np_in, inv_in, sm, (int)threadIdx.x);
    const float om = 1.f - th;
    long gid = (long)blockIdx.x * 256 + threadIdx.x;
    long stride = (long)gridDim.x * 256;
    for (long i = gid; i < n4; i += stride) {
        ushort4 hv = reinterpret_cast<const ushort4*>(h)[i];
        ushort4 rv = reinterpret_cast<const ushort4*>(r)[i];
        float4 o;
        o.x = th * bf2f(hv.x) + om * bf2f(rv.x);
        o.y = th * bf2f(hv.y) + om * bf2f(rv.y);
        o.z = th * bf2f(hv.z) + om * bf2f(rv.z);
        o.w = th * bf2f(hv.w) + om * bf2f(rv.w);
        reinterpret_cast<float4*>(out)[i] = o;
    }
}

// ---------------------------------------------------------------------------
extern "C" void kernel_launch(void* const* d_in, const int* in_sizes, int n_in,
                              void* d_out, int out_size, void* d_ws, size_t ws_size,
                              hipStream_t stream)
{
    const float* x       = (const float*)d_in[0];
    const float* adj     = (const float*)d_in[1];
    const float* Wres    = (const float*)d_in[2];
    const float* bres    = (const float*)d_in[3];
    const float* Wg0     = (const float*)d_in[4];
    const float* bg0     = (const float*)d_in[5];
    const float* Wrg0    = (const float*)d_in[6];
    const float* brg0    = (const float*)d_in[7];
    const float* logits0 = (const float*)d_in[8];
    const float* gumb0   = (const float*)d_in[9];
    const float* Wnl0    = (const float*)d_in[10];
    const float* bnl0    = (const float*)d_in[11];
    const float* Wwo0    = (const float*)d_in[12];
    const float* bwo0    = (const float*)d_in[13];
    const float* Wrw0    = (const float*)d_in[14];
    const float* brw0    = (const float*)d_in[15];
    const float* Wg1     = (const float*)d_in[16];
    const float* bg1     = (const float*)d_in[17];
    const float* Wrg1    = (const float*)d_in[18];
    const float* brg1    = (const float*)d_in[19];
    const float* logits1 = (const float*)d_in[20];
    const float* gumb1   = (const float*)d_in[21];
    const float* Wnl1    = (const float*)d_in[22];
    const float* bnl1    = (const float*)d_in[23];
    const float* Wwo1    = (const float*)d_in[24];
    const float* bwo1    = (const float*)d_in[25];
    const float* Wrw1    = (const float*)d_in[26];
    const float* brw1    = (const float*)d_in[27];

    float* out = (float*)d_out;

    // ---- workspace ----
    char* w = (char*)d_ws;
    auto alloc = [&](long bytes) { char* p = w; w += (bytes + 255) & ~255L; return p; };
    const long SLOT = (long)BNR * HH * 2;                 // 32 MB
    char* pool = alloc(5 * SLOT);                         // 160 MB
    __hip_bfloat16* Rbf  = (__hip_bfloat16*)alloc((long)BNR * DOUT * 2); // 8 MB
    __hip_bfloat16* adjb = (__hip_bfloat16*)alloc((long)NN * NN * 2);
    __hip_bfloat16* WT   = (__hip_bfloat16*)alloc(225280L * 2);
    float* partial0 = (float*)alloc(2048 * 4);
    float* partial1 = (float*)alloc(2048 * 4);
    float* partial2 = (float*)alloc(2048 * 4);
    float* partial3 = (float*)alloc(2048 * 4);
    float* bg0p    = (float*)alloc(256 * 4);
    float* brg0p   = (float*)alloc(256 * 4);
    float* crow0   = (float*)alloc(256 * 4);
    float* brgc1   = (float*)alloc(64 * 4);
    float* crow1   = (float*)alloc(64 * 4);
    float* cv0     = (float*)alloc(256 * 4);
    float* bv1g    = (float*)alloc(256 * 4);
    float* cv2     = (float*)alloc(64 * 4);
    float* ars     = (float*)alloc(512 * 4);
    float* bw1v    = (float*)alloc(256 * 4);
    float* bw1s    = (float*)alloc(256 * 4);
    unsigned int* cnt = (unsigned int*)alloc(16);

    auto S = [&](int i) { return pool + (long)i * SLOT; };
    __hip_bfloat16* xwrT = (__hip_bfloat16*)S(0);
    __hip_bfloat16* orw  = (__hip_bfloat16*)S(1);
    __hip_bfloat16* rw1  = (__hip_bfloat16*)(S(1) + (long)BNR * DOUT * 2);
    __hip_bfloat16* Radj = (__hip_bfloat16*)(S(1) + 2L * BNR * DOUT * 2);
    __hip_bfloat16* xg1  = (__hip_bfloat16*)S(2);
    __hip_bfloat16* T1x  = (__hip_bfloat16*)S(3);
    __hip_bfloat16* xbf  = (__hip_bfloat16*)S(4);
    __hip_bfloat16* xT   = (__hip_bfloat16*)(S(4) + (long)BNR * DIN * 2);
    __hip_bfloat16* T0   = (__hip_bfloat16*)(S(4) + 2L * BNR * DIN * 2);
    __hip_bfloat16* RbfT = (__hip_bfloat16*)(S(4) + 3L * BNR * DIN * 2);

    // transposed weights inside WT (element offsets)
    __hip_bfloat16* WresT   = WT;             // 64x64
    __hip_bfloat16* Wg0T    = WT + 4096;      // 256x64
    __hip_bfloat16* Wrg0T   = WT + 20480;     // 256x64  (NEGATED at prep)
    __hip_bfloat16* Wrw0T   = WT + 36864;     // 256x64
    __hip_bfloat16* Wg1T    = WT + 53248;     // 256x256 (th1 by sc1)
    __hip_bfloat16* Wrg1T   = WT + 118784;    // 256x64
    __hip_bfloat16* Wc1T    = WT + 135168;    // 64x256 (c1-scaled Wwo1^T; th2 by sc2)
    __hip_bfloat16* Wrw1T   = WT + 151552;    // 64x64
    __hip_bfloat16* Wg0pT   = WT + 155648;    // 256x64 (Wg0@(I+Wc0))^T; th0 sc0; th1 sc1
    __hip_bfloat16* Wrg0pT  = WT + 172032;    // 256x64 (Wrg0@(I+Wc0))^T; om0 sc0
    __hip_bfloat16* Wrgc1T  = WT + 188416;    // 64x64  (Wrg1@Wc1)^T; om2 sc2
    __hip_bfloat16* WcombT  = WT + 192512;    // 256x64 (th1*om0*Wrg0p + om1*Wrw0)^T by sc1
    __hip_bfloat16* WrwWg1T = WT + 208896;    // 256x64 (Wrw0@Wg1)^T; om1 by sc1

    const dim3 blk(256);
    const float invH = 1.0f / ((float)BNR * HH);
    const float invD = 1.0f / ((float)BNR * DOUT);

    // ---- prep (ONE launch) ----
    PrepArgs pa;
    pa.logits0 = logits0; pa.gumb0 = gumb0; pa.Wnl0 = Wnl0;
    pa.logits1 = logits1; pa.gumb1 = gumb1; pa.Wnl1 = Wnl1;
    pa.adj = adj; pa.adjb = (unsigned int*)adjb; pa.ars = ars;
    pa.x = x; pa.xbf = (unsigned short*)xbf; pa.xT = (unsigned short*)xT;
    pa.cnt = cnt;

    WTArgs wa;
    wa.src[0] = Wres; wa.dst[0] = (unsigned short*)WresT; wa.ci[0] = 0; wa.sgn[0] = 1.f;  wa.R[0] = 64;  wa.C[0] = 64;
    wa.src[1] = Wg0;  wa.dst[1] = (unsigned short*)Wg0T;  wa.ci[1] = 0; wa.sgn[1] = 1.f;  wa.R[1] = 64;  wa.C[1] = 256;
    wa.src[2] = Wrg0; wa.dst[2] = (unsigned short*)Wrg0T; wa.ci[2] = 0; wa.sgn[2] = -1.f; wa.R[2] = 64;  wa.C[2] = 256;
    wa.src[3] = Wrw0; wa.dst[3] = (unsigned short*)Wrw0T; wa.ci[3] = 0; wa.sgn[3] = 1.f;  wa.R[3] = 64;  wa.C[3] = 256;
    wa.src[4] = Wg1;  wa.dst[4] = (unsigned short*)Wg1T;  wa.ci[4] = 0; wa.sgn[4] = 1.f;  wa.R[4] = 256; wa.C[4] = 256;
    wa.src[5] = Wrg1; wa.dst[5] = (unsigned short*)Wrg1T; wa.ci[5] = 0; wa.sgn[5] = 1.f;  wa.R[5] = 64;  wa.C[5] = 256;
    wa.src[6] = Wwo1; wa.dst[6] = (unsigned short*)Wc1T;  wa.ci[6] = 2; wa.sgn[6] = 1.f;  wa.R[6] = 256; wa.C[6] = 64;
    wa.src[7] = Wrw1; wa.dst[7] = (unsigned short*)Wrw1T; wa.ci[7] = 0; wa.sgn[7] = 1.f;  wa.R[7] = 64;  wa.C[7] = 64;

    WFArgs wf;
    wf.Wsrc[0] = Wg0;  wf.Wbig[0] = Wwo0; wf.ci[0] = 1; wf.incl[0] = 1; wf.N[0] = 256;
    wf.dst[0] = (unsigned short*)Wg0pT;
    wf.Wsrc[1] = Wrg0; wf.Wbig[1] = Wwo0; wf.ci[1] = 1; wf.incl[1] = 1; wf.N[1] = 256;
    wf.dst[1] = (unsigned short*)Wrg0pT;
    wf.Wsrc[2] = Wrg1; wf.Wbig[2] = Wwo1; wf.ci[2] = 2; wf.incl[2] = 0; wf.N[2] = 64;
    wf.dst[2] = (unsigned short*)Wrgc1T;
    wf.Wsrc[3] = Wrw0; wf.Wbig[3] = Wg1;  wf.ci[3] = 0; wf.incl[3] = 0; wf.N[3] = 256;
    wf.dst[3] = (unsigned short*)WrwWg1T;

    FVArgs fv;
    fv.W[0] = Wwo0; fv.ci[0] = 1; fv.v[0] = bg0;  fv.base[0] = bg0;     fv.out[0] = bg0p;  fv.K[0] = 256; fv.N[0] = 256;
    fv.W[1] = Wwo0; fv.ci[1] = 1; fv.v[1] = brg0; fv.base[1] = brg0;    fv.out[1] = brg0p; fv.K[1] = 256; fv.N[1] = 256;
    fv.W[2] = Wwo0; fv.ci[2] = 0; fv.v[2] = bnl0; fv.base[2] = bwo0;    fv.out[2] = crow0; fv.K[2] = 256; fv.N[2] = 256;
    fv.W[3] = Wwo1; fv.ci[3] = 2; fv.v[3] = brg1; fv.base[3] = nullptr; fv.out[3] = brgc1; fv.K[3] = 256; fv.N[3] = 64;
    fv.W[4] = Wwo1; fv.ci[4] = 0; fv.v[4] = bnl1; fv.base[4] = bwo1;    fv.out[4] = crow1; fv.K[4] = 256; fv.N[4] = 64;
    fv.W[5] = Wg1;  fv.ci[5] = 0; fv.v[5] = brw0; fv.base[5] = nullptr; fv.out[5] = bw1v;  fv.K[5] = 256; fv.N[5] = 256;

    hipLaunchKernelGGL(prep_k, dim3(NN + 8 * BB + 128 + 256 + 256), blk, 0, stream,
                       pa, wa, wf, fv);

    // res = x @ Wres + bres -> Rbf + RbfT
    hipLaunchKernelGGL((gemm_res_k<128, 64, 4, 2>), dim3(1, BNR / 128, 1), blk, 0, stream,
                       xbf, WresT, bres, Rbf, RbfT, BNR, DOUT, DIN);

    // T0 = adj@x AND Radj = adj@Rbf (fused)
    hipLaunchKernelGGL(t0radj_k, dim3(BB * 4), blk, 0, stream,
                       adjb, xT, RbfT, T0, Radj);

    // D0 (+ sc0 last-block)
    hipLaunchKernelGGL((dual1_k<64, 128, 2, 4>), dim3(2 * BNR / 64), blk, 0, stream,
                       T0, Wg0T, DIN, Rbf, Wrg0T, DOUT, bg0, brg0, partial0, BNR, HH,
                       cnt + 0, invH,
                       (unsigned short*)Wg0pT, (unsigned short*)Wrg0pT,
                       bg0p, brg0p, crow0, cv0);

    // W0 (+ sc1 last-block)
    hipLaunchKernelGGL((wave2T_k<64, 128, 2, 4>), dim3(2 * BNR / 64), blk, 0, stream,
                       T0, Wg0pT, DIN, Rbf, Wrg0pT, DOUT, Rbf, Wrw0T, DOUT,
                       cv0, brw0, xwrT, partial1, BNR, HH,
                       cnt + 1, invH,
                       (unsigned short*)Wg1T, (const unsigned short*)Wrw0T,
                       (unsigned short*)Wrg0pT, (unsigned short*)WcombT,
                       (unsigned short*)Wg0pT, (unsigned short*)WrwWg1T,
                       bg1, brw0, cv0, bw1v, bv1g, bw1s);

    // T1x = adj @ xwr (batched, XCD-grouped, pipelined; 128x64 tiles)
    hipLaunchKernelGGL((gemm_bt_swz_k<128, 64, 4, 2, 4, 16, 8>), dim3(BB * 16), blk, 0, stream,
                       adjb, xwrT, T1x, NN, HH, NN, 0, (long)HH * NN, (long)NN * HH);

    // gmix5 (+ sc2 last-block)
    hipLaunchKernelGGL((gmix5_k<64, 128, 2, 4>), dim3(2 * BNR / 64), blk, 0, stream,
                       T1x, Wg1T, HH,
                       Radj, WrwWg1T, DOUT,
                       T0, Wg0pT, DIN,
                       Rbf, WcombT, DOUT,
                       Rbf, Wrg1T, DOUT,
                       bv1g, brg1, ars, bw1s, xg1, partial2, BNR, HH,
                       cnt + 2, invH,
                       (unsigned short*)Wc1T, (unsigned short*)Wrgc1T,
                       brgc1, crow1, cv2);

    // F: orw = xg1@(th2*Wc1) + Rbf@(om2*Wrgc1) + cv2 ; rw1 = Rbf@Wrw1 + brw1
    hipLaunchKernelGGL((wave2_k<64, 64, 2, 2>), dim3(1, BNR / 64), blk, 0, stream,
                       xg1, Wc1T, HH, Rbf, Wrgc1T, DOUT, Rbf, Wrw1T, DIN,
                       cv2, brw1, orw, rw1, partial3, BNR, DOUT);

    // final mix -> fp32 out
    hipLaunchKernelGGL(mixfinal_k, dim3(2048), blk, 0, stream,
                       (const unsigned short*)orw, (const unsigned short*)rw1,
                       partial3, 1024, invD, out, (long)BNR * DOUT / 4);
}

// Round 16
// 157.983 us; speedup vs baseline: 5.1584x; 5.1584x over previous
//
#include <hip/hip_runtime.h>
#include <hip/hip_bf16.h>
#include <math.h>

#define BB   128
#define NN   512
#define DIN  64
#define HH   256
#define DOUT 64
#define BNR  (BB * NN)          // 65536 rows

typedef float  f32x4  __attribute__((ext_vector_type(4)));
typedef __bf16 bf16x8 __attribute__((ext_vector_type(8)));

#define GLP(p)  ((const __attribute__((address_space(1))) void*)(p))
#define LDSP(p) ((__attribute__((address_space(3))) void*)(p))

// Haar/db1 'zero' DWT patterns, levels 1..3, FULL_LEN=8
__constant__ float PAT[3][8] = {
    {0.70710678f, 0.70710678f, 0.f, 0.f, 0.f, 0.f, 0.f, 0.f},
    {0.5f,        0.70710678f, 0.f, 0.5f, 0.f, 0.f, 0.f, 0.f},
    {0.35355339f, 0.70710678f, 0.f, 0.f, 0.f, 0.5f, 0.f, 0.35355339f}
};

__device__ __forceinline__ unsigned short f2bfu(float x) {
    __hip_bfloat16 b = __float2bfloat16(x);
    unsigned short u;
    __builtin_memcpy(&u, &b, 2);
    return u;
}
__device__ __forceinline__ float bf2f(unsigned short u) {
    unsigned int v = ((unsigned int)u) << 16;
    float f;
    __builtin_memcpy(&f, &v, 4);
    return f;
}

// ---------------------------------------------------------------------------
// In-kernel th = sigmoid(mean diff) — same tree order everywhere.
// ---------------------------------------------------------------------------
__device__ __forceinline__ float block_th(const float* __restrict__ partial, int np,
                                          float inv_n, float* red, int tid)
{
    float s = 0.f;
    for (int i = tid; i < np; i += 256) s += partial[i];
    red[tid] = s;
    __syncthreads();
    for (int o = 128; o > 0; o >>= 1) {
        if (tid < o) red[tid] += red[tid + o];
        __syncthreads();
    }
    float th = 1.f / (1.f + expf(-red[0] * inv_n));
    __syncthreads();
    return th;
}

// ---------------------------------------------------------------------------
// Coalesced bf16 tile write via LDS staging (proven round 4). Row-major.
// ---------------------------------------------------------------------------
template<int BM, int BN, int FM, int FN>
__device__ __forceinline__ void write_tile(char* lds, f32x4 (&a)[FM][FN],
                                           __hip_bfloat16* __restrict__ C,
                                           long base, int N, int tid)
{
    const int wave = tid >> 6;
    const int lane = tid & 63;
    const int wm = wave >> 1, wn = wave & 1;
    const int lc = lane & 15;
    const int lr4 = (lane >> 4) << 2;
    __syncthreads();
    #pragma unroll
    for (int j = 0; j < FN; ++j) {
        int colb = (wn * (FN * 16) + j * 16 + lc) * 2;
        #pragma unroll
        for (int i = 0; i < FM; ++i) {
            int row0 = wm * (FM * 16) + i * 16 + lr4;
            #pragma unroll
            for (int r = 0; r < 4; ++r) {
                int row = row0 + r;
                *reinterpret_cast<unsigned short*>(
                    lds + row * (BN * 2) + (colb ^ (((row >> 2) & 3) << 5))) =
                    f2bfu(a[i][j][r]);
            }
        }
    }
    __syncthreads();
    const int TPR = BN / 8;
    const int RPP = 256 / TPR;
    #pragma unroll
    for (int p = 0; p < BM / RPP; ++p) {
        int row = p * RPP + tid / TPR;
        int cb = (tid % TPR) * 16;
        int pb = cb ^ (((row >> 2) & 3) << 5);
        uint4 v = *reinterpret_cast<const uint4*>(lds + row * (BN * 2) + pb);
        *reinterpret_cast<uint4*>(reinterpret_cast<char*>(C + base + (long)row * N) + cb) = v;
    }
}

// ---------------------------------------------------------------------------
// Transposed tile write (proven round 11).
// ---------------------------------------------------------------------------
template<int BM, int BN, int FM, int FN>
__device__ __forceinline__ void write_tileT(char* lds, f32x4 (&a)[FM][FN],
                                            __hip_bfloat16* __restrict__ CT,
                                            long baseT, int ldT, int tid)
{
    const int wave = tid >> 6;
    const int lane = tid & 63;
    const int wm = wave >> 1, wn = wave & 1;
    const int lc = lane & 15;
    const int lr4 = (lane >> 4) << 2;
    __syncthreads();
    #pragma unroll
    for (int j = 0; j < FN; ++j) {
        int c = wn * (FN * 16) + j * 16 + lc;
        int cbase = c * (BM * 2);
        int swz = ((c >> 2) & 3) << 5;
        #pragma unroll
        for (int i = 0; i < FM; ++i) {
            int m0 = wm * (FM * 16) + i * 16 + lr4;
            #pragma unroll
            for (int r = 0; r < 4; ++r) {
                int m = m0 + r;
                *reinterpret_cast<unsigned short*>(lds + cbase + ((m * 2) ^ swz)) =
                    f2bfu(a[i][j][r]);
            }
        }
    }
    __syncthreads();
    const int TPR = BM / 8;
    const int RPP = 256 / TPR;
    #pragma unroll
    for (int p = 0; p < BN / RPP; ++p) {
        int c = p * RPP + tid / TPR;
        int tb = (tid % TPR) * 16;
        int pb = tb ^ (((c >> 2) & 3) << 5);
        uint4 v = *reinterpret_cast<const uint4*>(lds + c * (BM * 2) + pb);
        *reinterpret_cast<uint4*>(reinterpret_cast<char*>(CT + baseT + (long)c * ldT) + tb) = v;
    }
}

// ---------------------------------------------------------------------------
// staging of one K=64 slab of A(BM rows) + B(BN rows) into swizzled LDS
// ---------------------------------------------------------------------------
template<int BM, int BN>
__device__ __forceinline__ void stage_tiles(const __hip_bfloat16* __restrict__ Ab,
                                            const __hip_bfloat16* __restrict__ Bb,
                                            char* AsB, char* BsB,
                                            int m0, int n0, int k0, int KA, int KB,
                                            int wave, int lane)
{
    const int NCH = (BM + BN) / 32;
    const int lr = lane >> 3;
    const int ls = lane & 7;
    #pragma unroll
    for (int cc = 0; cc < NCH; ++cc) {
        int c = wave * NCH + cc;
        const __hip_bfloat16* src;
        char* ldsb;
        if (c < BM / 8) {
            int r = c * 8 + lr;
            ldsb = AsB + c * 1024;
            src = Ab + ((long)(m0 + r) * KA + k0 + ((ls ^ (r & 7)) << 3));
        } else {
            int c2 = c - BM / 8;
            int r = c2 * 8 + lr;
            ldsb = BsB + c2 * 1024;
            src = Bb + ((long)(n0 + r) * KB + k0 + ((ls ^ (r & 7)) << 3));
        }
        __builtin_amdgcn_global_load_lds(GLP(src), LDSP(ldsb), 16, 0, 0);
    }
}

template<int BM, int BN, int FM, int FN>
__device__ __forceinline__ void mfma_tiles(char* AsB, char* BsB,
                                           f32x4 (&acc)[FM][FN], int wave, int lane)
{
    const int wm = wave >> 1, wn = wave & 1;
    #pragma unroll
    for (int ksl = 0; ksl < 2; ++ksl) {
        bf16x8 af[FM], bfr[FN];
        #pragma unroll
        for (int i = 0; i < FM; ++i) {
            int row = wm * (FM * 16) + i * 16 + (lane & 15);
            int off = (ksl * 64 + ((lane >> 4) << 4)) ^ ((row & 7) << 4);
            af[i] = *reinterpret_cast<const bf16x8*>(AsB + row * 128 + off);
        }
        #pragma unroll
        for (int j = 0; j < FN; ++j) {
            int row = wn * (FN * 16) + j * 16 + (lane & 15);
            int off = (ksl * 64 + ((lane >> 4) << 4)) ^ ((row & 7) << 4);
            bfr[j] = *reinterpret_cast<const bf16x8*>(BsB + row * 128 + off);
        }
        #pragma unroll
        for (int i = 0; i < FM; ++i)
            #pragma unroll
            for (int j = 0; j < FN; ++j)
                acc[i][j] = __builtin_amdgcn_mfma_f32_16x16x32_bf16(
                    af[i], bfr[j], acc[i][j], 0, 0, 0);
    }
}

// ---------------------------------------------------------------------------
// Pipelined multi-step runner (round-13 proven: __syncthreads only).
// ---------------------------------------------------------------------------
template<int BM, int BN, int FM, int FN, int NS, int NA>
__device__ __forceinline__ void pipe_run(
    const __hip_bfloat16* const (&sA)[NS], const __hip_bfloat16* const (&sB)[NS],
    const int (&sK)[NS], const int (&sk0)[NS],
    char* buf0, char* buf1,
    f32x4 (&acc0)[FM][FN], f32x4 (&acc1)[FM][FN],
    int m0, int n0, int wave, int lane)
{
    constexpr int BOFF = BM * 128;
    stage_tiles<BM, BN>(sA[0], sB[0], buf0, buf0 + BOFF, m0, n0, sk0[0],
                        sK[0], sK[0], wave, lane);
    __syncthreads();
    #pragma unroll
    for (int t = 0; t < NS; ++t) {
        char* bc = (t & 1) ? buf1 : buf0;
        if (t + 1 < NS) {
            char* bn = (t & 1) ? buf0 : buf1;
            stage_tiles<BM, BN>(sA[t + 1], sB[t + 1], bn, bn + BOFF, m0, n0,
                                sk0[t + 1], sK[t + 1], sK[t + 1], wave, lane);
        }
        if (t < NA) mfma_tiles<BM, BN, FM, FN>(bc, bc + BOFF, acc0, wave, lane);
        else        mfma_tiles<BM, BN, FM, FN>(bc, bc + BOFF, acc1, wave, lane);
        __syncthreads();
    }
}

// ---------------------------------------------------------------------------
// transpose-convert fp32 (R,C) -> bf16 (C,R), optional per-src-row scale + sign
// ---------------------------------------------------------------------------
__device__ __forceinline__ void tcvt_body(const float* __restrict__ in,
                                          unsigned short* __restrict__ out,
                                          const float* cs, float us,
                                          int R, int C, int r0, int c0)
{
    __shared__ float t[64][65];
    int tr = threadIdx.x >> 6;
    int tc = threadIdx.x & 63;
    #pragma unroll
    for (int i = 0; i < 16; ++i) {
        int r = i * 4 + tr;
        t[r][tc] = in[(long)(r0 + r) * C + c0 + tc];
    }
    __syncthreads();
    float sc = (cs ? cs[r0 + tc] : 1.0f) * us;
    #pragma unroll
    for (int i = 0; i < 16; ++i) {
        int r = i * 4 + tr;
        out[(long)(c0 + r) * R + r0 + tc] = f2bfu(t[tc][r] * sc);
    }
}

// coeff recompute (per block, 256 threads)
__device__ __forceinline__ void coeff_local(const float* lg, const float* gb,
                                            const float* Wn, float* cof, int t)
{
    float l0 = lg[0] + gb[t * 3 + 0];
    float l1 = lg[1] + gb[t * 3 + 1];
    float l2 = lg[2] + gb[t * 3 + 2];
    int bl = 0;
    float bv = l0;
    if (l1 > bv) { bv = l1; bl = 1; }
    if (l2 > bv) { bv = l2; bl = 2; }
    float s = 0.f;
    #pragma unroll
    for (int q = 0; q < 8; ++q) s += Wn[t * 8 + q] * PAT[bl][q];
    cof[t] = s;
}

struct WTArgs {
    const float* src[8];
    unsigned short* dst[8];
    int ci[8];
    float sgn[8];
    int R[8], C[8];
};
struct WFArgs {
    const float* Wsrc[4];
    const float* Wbig[4];
    int ci[4], incl[4], N[4];
    unsigned short* dst[4];
};
struct FVArgs {
    const float* W[6];
    int ci[6];
    const float* v[6];
    const float* base[6];
    float* out[6];
    int K[6], N[6];
};
struct PrepArgs {
    const float *logits0, *gumb0, *Wnl0, *logits1, *gumb1, *Wnl1;
    const float* adj;
    unsigned int* adjb;
    float* ars;
    const float* x;
    unsigned short *xbf, *xT;
};

// ---------------------------------------------------------------------------
// prep_k: ONE launch: adj cvt+rowsum (512) | x cvt+T (1024) |
// weight transposes (128) | weight folds (256) | vector folds (256)
// coeff vectors recomputed locally by blocks that need them.
// ---------------------------------------------------------------------------
__global__ __launch_bounds__(256) void prep_k(PrepArgs p, WTArgs wa, WFArgs wf, FVArgs fv)
{
    __shared__ float cofA[256];
    __shared__ float cofB[256];
    __shared__ float redu[256];
    const int b = blockIdx.x;
    const int t = threadIdx.x;
    if (b < NN) {
        float2 v = reinterpret_cast<const float2*>(p.adj)[b * 256 + t];
        p.adjb[b * 256 + t] = (unsigned int)f2bfu(v.x) | ((unsigned int)f2bfu(v.y) << 16);
        redu[t] = v.x + v.y;
        __syncthreads();
        for (int o = 128; o > 0; o >>= 1) {
            if (t < o) redu[t] += redu[t + o];
            __syncthreads();
        }
        if (t == 0) p.ars[b] = redu[0];
    } else if (b < NN + 8 * BB) {
        __shared__ float tl[64][65];
        int tt = b - NN;
        int bz = tt >> 3;
        int r0 = (tt & 7) * 64;
        const long base = (long)bz * NN * DIN;
        const int tr4 = t >> 6;
        const int tc  = t & 63;
        #pragma unroll
        for (int i = 0; i < 16; ++i) {
            int r = i * 4 + tr4;
            float v = p.x[base + (long)(r0 + r) * DIN + tc];
            tl[r][tc] = v;
            p.xbf[base + (long)(r0 + r) * DIN + tc] = f2bfu(v);
        }
        __syncthreads();
        #pragma unroll
        for (int i = 0; i < 16; ++i) {
            int d = i * 4 + tr4;
            p.xT[base + (long)d * NN + r0 + tc] = f2bfu(tl[tc][d]);
        }
    } else if (b < NN + 8 * BB + 128) {
        int xg = b - NN - 8 * BB;
        int wgt = xg >> 4;
        int tl2 = xg & 15;
        int R = wa.R[wgt], C = wa.C[wgt];
        int tilesX = C >> 6;
        int tiles = (R >> 6) * tilesX;
        if (tl2 >= tiles) return;
        const float* cs = nullptr;
        if (wa.ci[wgt]) {
            if (wa.ci[wgt] == 1) coeff_local(p.logits0, p.gumb0, p.Wnl0, cofA, t);
            else                 coeff_local(p.logits1, p.gumb1, p.Wnl1, cofA, t);
            __syncthreads();
            cs = cofA;
        }
        tcvt_body(wa.src[wgt], wa.dst[wgt], cs, wa.sgn[wgt], R, C,
                  (tl2 / tilesX) * 64, (tl2 % tilesX) * 64);
    } else if (b < NN + 8 * BB + 128 + 256) {
        int xg = b - NN - 8 * BB - 128;
        int cs = xg >> 6;
        int m = xg & 63;
        float cv = 1.0f;
        if (wf.ci[cs]) {
            if (wf.ci[cs] == 1) coeff_local(p.logits0, p.gumb0, p.Wnl0, cofA, t);
            else                coeff_local(p.logits1, p.gumb1, p.Wnl1, cofA, t);
            __syncthreads();
            cv = cofA[t];
        }
        cofB[t] = wf.Wsrc[cs][m * 256 + t] * cv;
        __syncthreads();
        int n = t;
        int N = wf.N[cs];
        if (n >= N) return;
        float s = wf.incl[cs] ? wf.Wsrc[cs][m * 256 + n] : 0.f;
        const float* Wb = wf.Wbig[cs];
        #pragma unroll 8
        for (int k = 0; k < 256; ++k)
            s += cofB[k] * Wb[(long)k * N + n];
        wf.dst[cs][n * 64 + m] = f2bfu(s);
    } else {
        int n = b - (NN + 8 * BB + 128 + 256);
        coeff_local(p.logits0, p.gumb0, p.Wnl0, cofA, t);
        coeff_local(p.logits1, p.gumb1, p.Wnl1, cofB, t);
        __syncthreads();
        for (int cs = 0; cs < 6; ++cs) {
            __syncthreads();
            if (n >= fv.N[cs]) continue;
            float s = 0.f;
            if (t < fv.K[cs]) {
                float cc = (fv.ci[cs] == 1) ? cofA[t] : (fv.ci[cs] == 2 ? cofB[t] : 1.0f);
                s = fv.v[cs][t] * cc * fv.W[cs][(long)t * fv.N[cs] + n];
            }
            redu[t] = s;
            __syncthreads();
            for (int o = 128; o > 0; o >>= 1) {
                if (t < o) redu[t] += redu[t + o];
                __syncthreads();
            }
            if (t == 0)
                fv.out[cs][n] = (fv.base[cs] ? fv.base[cs][n] : 0.f) + redu[0];
        }
    }
}

// ---------------------------------------------------------------------------
// sc kernels (separate launches — cheap vs per-block device fences)
// ---------------------------------------------------------------------------
__global__ __launch_bounds__(256) void sc0_k(
    const float* __restrict__ partial, int np, float inv_n,
    unsigned short* __restrict__ Wa, unsigned short* __restrict__ Wb,
    const float* __restrict__ bg0p, const float* __restrict__ brg0p,
    const float* __restrict__ crow0, float* __restrict__ cv0)
{
    __shared__ float red[256];
    float th = block_th(partial, np, inv_n, red, threadIdx.x);
    float om = 1.f - th;
    int g = blockIdx.x * 256 + threadIdx.x;
    Wa[g] = f2bfu(th * bf2f(Wa[g]));
    Wb[g] = f2bfu(om * bf2f(Wb[g]));
    if (g < 256) cv0[g] = th * bg0p[g] + om * brg0p[g] + crow0[g];
}

__global__ __launch_bounds__(256) void sc1_k(
    const float* __restrict__ partial, int np, float inv_n,
    unsigned short* __restrict__ Wg1T,
    const unsigned short* __restrict__ Wrw0T, const unsigned short* __restrict__ Wrg0pT,
    unsigned short* __restrict__ WcombT,
    unsigned short* __restrict__ Wg0pT,
    unsigned short* __restrict__ WrwWg1T,
    const float* __restrict__ bg1, const float* __restrict__ brw0,
    const float* __restrict__ cv0, const float* __restrict__ bw1v,
    float* __restrict__ bv1g, float* __restrict__ bw1s)
{
    __shared__ float red[256];
    float th = block_th(partial, np, inv_n, red, threadIdx.x);
    float om = 1.f - th;
    int g = blockIdx.x * 256 + threadIdx.x;
    Wg1T[g] = f2bfu(th * bf2f(Wg1T[g]));
    if (g < 16384) {
        WcombT[g]  = f2bfu(th * bf2f(Wrg0pT[g]) + om * bf2f(Wrw0T[g]));
        Wg0pT[g]   = f2bfu(th * bf2f(Wg0pT[g]));
        WrwWg1T[g] = f2bfu(om * bf2f(WrwWg1T[g]));
    }
    if (g < 256) {
        bv1g[g] = bg1[g] + om * brw0[g] + th * cv0[g];
        bw1s[g] = om * bw1v[g];
    }
}

__global__ __launch_bounds__(256) void sc2_k(
    const float* __restrict__ partial, int np, float inv_n,
    unsigned short* __restrict__ Wc1T, unsigned short* __restrict__ Wrgc1T,
    const float* __restrict__ brgc1, const float* __restrict__ crow1,
    float* __restrict__ cv2)
{
    __shared__ float red[256];
    float th = block_th(partial, np, inv_n, red, threadIdx.x);
    float om = 1.f - th;
    int g = blockIdx.x * 256 + threadIdx.x;
    Wc1T[g] = f2bfu(th * bf2f(Wc1T[g]));
    if (g < 4096) Wrgc1T[g] = f2bfu(om * bf2f(Wrgc1T[g]));
    if (g < 64) cv2[g] = om * brgc1[g] + crow1[g];
}

// ---------------------------------------------------------------------------
// Rbf producer: C = A@B + bias, row-major AND per-batch transposed.
// ---------------------------------------------------------------------------
template<int BM, int BN, int FM, int FN>
__global__ __launch_bounds__(256) void gemm_res_k(
    const __hip_bfloat16* __restrict__ A, const __hip_bfloat16* __restrict__ Bt,
    const float* __restrict__ bias,
    __hip_bfloat16* __restrict__ Cb, __hip_bfloat16* __restrict__ CbT,
    int M, int N, int K)
{
    __shared__ __attribute__((aligned(128))) char lds[(BM + BN) * 128];
    char* AsB = lds;
    char* BsB = lds + BM * 128;

    const int m0 = blockIdx.y * BM;
    const int tid  = threadIdx.x;
    const int wave = tid >> 6;
    const int lane = tid & 63;
    const int wn = wave & 1;

    f32x4 acc[FM][FN];
    #pragma unroll
    for (int i = 0; i < FM; ++i)
        #pragma unroll
        for (int j = 0; j < FN; ++j)
            acc[i][j] = (f32x4){0.f, 0.f, 0.f, 0.f};

    for (int k0 = 0; k0 < K; k0 += 64) {
        stage_tiles<BM, BN>(A, Bt, AsB, BsB, m0, 0, k0, K, K, wave, lane);
        __syncthreads();
        mfma_tiles<BM, BN, FM, FN>(AsB, BsB, acc, wave, lane);
        __syncthreads();
    }

    const int lc = lane & 15;
    #pragma unroll
    for (int j = 0; j < FN; ++j) {
        float bv = bias[wn * (FN * 16) + j * 16 + lc];
        #pragma unroll
        for (int i = 0; i < FM; ++i)
            #pragma unroll
            for (int r = 0; r < 4; ++r)
                acc[i][j][r] += bv;
    }
    write_tile<BM, BN, FM, FN>(lds, acc, Cb, (long)m0 * N, N, tid);
    long baseT = (long)(m0 / NN) * ((long)N * NN) + (m0 % NN);
    write_tileT<BM, BN, FM, FN>(lds, acc, CbT, baseT, NN, tid);
}

// ---------------------------------------------------------------------------
// t0radj_k: fused adj@[x | Rbf] — shared A staging, two accumulators (rd 14).
// ---------------------------------------------------------------------------
__global__ __launch_bounds__(256) void t0radj_k(
    const __hip_bfloat16* __restrict__ adjb,
    const __hip_bfloat16* __restrict__ xT,
    const __hip_bfloat16* __restrict__ RbfT,
    __hip_bfloat16* __restrict__ T0,
    __hip_bfloat16* __restrict__ Radj)
{
    constexpr int BM = 128, BN = 64;
    constexpr int ABYTES = BM * 128;
    constexpr int BBYTES = BN * 128;
    constexpr int BUF = ABYTES + 2 * BBYTES;
    __shared__ __attribute__((aligned(128))) char lds[2 * BUF];

    const int d   = blockIdx.x;
    const int xcd = d & 7;
    const int q   = d >> 3;
    const int t   = q & 3;
    const int bz  = xcd + ((q >> 2) << 3);
    const int m0  = t * BM;

    const __hip_bfloat16* B1 = xT + (long)bz * (64L * NN);
    const __hip_bfloat16* B2 = RbfT + (long)bz * (64L * NN);

    const int tid  = threadIdx.x;
    const int wave = tid >> 6;
    const int lane = tid & 63;
    const int lr = lane >> 3;
    const int ls = lane & 7;

    f32x4 accA[4][2], accB[4][2];
    #pragma unroll
    for (int i = 0; i < 4; ++i)
        #pragma unroll
        for (int j = 0; j < 2; ++j) {
            accA[i][j] = (f32x4){0.f, 0.f, 0.f, 0.f};
            accB[i][j] = (f32x4){0.f, 0.f, 0.f, 0.f};
        }

    auto stage2 = [&](char* buf, int k0) {
        #pragma unroll
        for (int cc = 0; cc < 8; ++cc) {
            int c = wave * 8 + cc;
            const __hip_bfloat16* src;
            char* ldsb;
            if (c < 16) {
                int r = c * 8 + lr;
                ldsb = buf + c * 1024;
                src = adjb + ((long)(m0 + r) * NN + k0 + ((ls ^ (r & 7)) << 3));
            } else if (c < 24) {
                int r = (c - 16) * 8 + lr;
                ldsb = buf + ABYTES + (c - 16) * 1024;
                src = B1 + ((long)r * NN + k0 + ((ls ^ (r & 7)) << 3));
            } else {
                int r = (c - 24) * 8 + lr;
                ldsb = buf + ABYTES + BBYTES + (c - 24) * 1024;
                src = B2 + ((long)r * NN + k0 + ((ls ^ (r & 7)) << 3));
            }
            __builtin_amdgcn_global_load_lds(GLP(src), LDSP(ldsb), 16, 0, 0);
        }
    };

    stage2(lds, 0);
    __syncthreads();
    #pragma unroll
    for (int s = 0; s < 8; ++s) {
        char* bc = lds + (s & 1) * BUF;
        if (s + 1 < 8) stage2(lds + ((s + 1) & 1) * BUF, (s + 1) * 64);
        mfma_tiles<BM, BN, 4, 2>(bc, bc + ABYTES, accA, wave, lane);
        mfma_tiles<BM, BN, 4, 2>(bc, bc + ABYTES + BBYTES, accB, wave, lane);
        __syncthreads();
    }

    long base = (long)bz * ((long)NN * BN) + (long)m0 * BN;
    write_tile<BM, BN, 4, 2>(lds, accA, T0, base, BN, tid);
    write_tile<BM, BN, 4, 2>(lds, accB, Radj, base, BN, tid);
}

// ---------------------------------------------------------------------------
// Batched pipelined GEMM with XCD-grouped block swizzle (round 13).
// ---------------------------------------------------------------------------
template<int BM, int BN, int FM, int FN, int GX, int NB, int NS>
__global__ __launch_bounds__(256) void gemm_bt_swz_k(
    const __hip_bfloat16* __restrict__ A, const __hip_bfloat16* __restrict__ Bt,
    __hip_bfloat16* __restrict__ Cb,
    int M, int N, int K, long sA, long sB, long sC)
{
    __shared__ __attribute__((aligned(128))) char lds[2 * (BM + BN) * 128];

    const int d   = blockIdx.x;
    const int xcd = d & 7;
    const int q   = d >> 3;
    const int t   = q % NB;
    const int bz  = xcd + ((q / NB) << 3);
    const int n0  = (t % GX) * BN;
    const int m0  = (t / GX) * BM;

    const __hip_bfloat16* Ab = A + (long)bz * sA;
    const __hip_bfloat16* Bb = Bt + (long)bz * sB;

    const int tid  = threadIdx.x;
    const int wave = tid >> 6;
    const int lane = tid & 63;

    f32x4 acc[FM][FN];
    #pragma unroll
    for (int i = 0; i < FM; ++i)
        #pragma unroll
        for (int j = 0; j < FN; ++j)
            acc[i][j] = (f32x4){0.f, 0.f, 0.f, 0.f};

    const __hip_bfloat16* pA[NS];
    const __hip_bfloat16* pB[NS];
    int pK[NS], pk0[NS];
    #pragma unroll
    for (int s = 0; s < NS; ++s) { pA[s] = Ab; pB[s] = Bb; pK[s] = K; pk0[s] = s * 64; }

    pipe_run<BM, BN, FM, FN, NS, NS>(pA, pB, pK, pk0,
                                     lds, lds + (BM + BN) * 128,
                                     acc, acc, m0, n0, wave, lane);

    write_tile<BM, BN, FM, FN>(lds, acc, Cb, (long)bz * sC + (long)m0 * N + n0, N, tid);
}

// ---------------------------------------------------------------------------
// dual1_k (D0): ONE accumulator, pair-swizzled, pipelined (2 steps).
// ---------------------------------------------------------------------------
template<int BM, int BN, int FM, int FN>
__global__ __launch_bounds__(256) void dual1_k(
    const __hip_bfloat16* __restrict__ A0, const __hip_bfloat16* __restrict__ B0, int K0,
    const __hip_bfloat16* __restrict__ A1, const __hip_bfloat16* __restrict__ B1, int K1,
    const float* __restrict__ b1, const float* __restrict__ b2,
    float* __restrict__ partial, int M, int N)
{
    __shared__ __attribute__((aligned(128))) char lds[2 * (BM + BN) * 128];

    const int d   = blockIdx.x;
    const int q   = d >> 3;
    const int nx  = q & 1;
    const int my  = (d & 7) + ((q >> 1) << 3);
    const int m0  = my * BM;
    const int n0  = nx * BN;

    const int tid  = threadIdx.x;
    const int wave = tid >> 6;
    const int lane = tid & 63;
    const int wn = wave & 1;

    f32x4 acc[FM][FN];
    #pragma unroll
    for (int i = 0; i < FM; ++i)
        #pragma unroll
        for (int j = 0; j < FN; ++j)
            acc[i][j] = (f32x4){0.f, 0.f, 0.f, 0.f};

    const __hip_bfloat16* pA[2] = {A0, A1};
    const __hip_bfloat16* pB[2] = {B0, B1};
    int pK[2] = {K0, K1};
    int pk0[2] = {0, 0};
    pipe_run<BM, BN, FM, FN, 2, 2>(pA, pB, pK, pk0,
                                   lds, lds + (BM + BN) * 128,
                                   acc, acc, m0, n0, wave, lane);

    const int lc = lane & 15;
    float dsum = 0.f;
    #pragma unroll
    for (int j = 0; j < FN; ++j) {
        int col = n0 + wn * (FN * 16) + j * 16 + lc;
        float bd = b1[col] - b2[col];
        #pragma unroll
        for (int i = 0; i < FM; ++i)
            #pragma unroll
            for (int r = 0; r < 4; ++r) {
                float dd = acc[i][j][r] + bd;
                dsum += dd * dd;
            }
    }

    float* red = (float*)lds;
    red[tid] = dsum;
    __syncthreads();
    for (int o = 128; o > 0; o >>= 1) {
        if (tid < o) red[tid] += red[tid + o];
        __syncthreads();
    }
    if (tid == 0) partial[my * 2 + nx] = red[0];
}

// ---------------------------------------------------------------------------
// wave2T_k (W0): 3 pipelined steps {acc0,acc0,acc1}; writes C1 transposed.
// ---------------------------------------------------------------------------
template<int BM, int BN, int FM, int FN>
__global__ __launch_bounds__(256) void wave2T_k(
    const __hip_bfloat16* __restrict__ A0, const __hip_bfloat16* __restrict__ B0, int K0,
    const __hip_bfloat16* __restrict__ A1, const __hip_bfloat16* __restrict__ B1, int K1,
    const __hip_bfloat16* __restrict__ A2, const __hip_bfloat16* __restrict__ B2, int K2,
    const float* __restrict__ cv, const float* __restrict__ b2v,
    __hip_bfloat16* __restrict__ C1T, float* __restrict__ partial_out, int M, int N)
{
    __shared__ __attribute__((aligned(128))) char lds[2 * (BM + BN) * 128];

    const int d   = blockIdx.x;
    const int q   = d >> 3;
    const int nx  = q & 1;
    const int my  = (d & 7) + ((q >> 1) << 3);
    const int m0  = my * BM;
    const int n0  = nx * BN;

    const int tid  = threadIdx.x;
    const int wave = tid >> 6;
    const int lane = tid & 63;
    const int wn = wave & 1;

    f32x4 acc0[FM][FN], acc1[FM][FN];
    #pragma unroll
    for (int i = 0; i < FM; ++i)
        #pragma unroll
        for (int j = 0; j < FN; ++j) {
            acc0[i][j] = (f32x4){0.f, 0.f, 0.f, 0.f};
            acc1[i][j] = (f32x4){0.f, 0.f, 0.f, 0.f};
        }

    const __hip_bfloat16* pA[3] = {A0, A1, A2};
    const __hip_bfloat16* pB[3] = {B0, B1, B2};
    int pK[3] = {K0, K1, K2};
    int pk0[3] = {0, 0, 0};
    pipe_run<BM, BN, FM, FN, 3, 2>(pA, pB, pK, pk0,
                                   lds, lds + (BM + BN) * 128,
                                   acc0, acc1, m0, n0, wave, lane);

    const int lc = lane & 15;
    float dsum = 0.f;
    #pragma unroll
    for (int j = 0; j < FN; ++j) {
        int col = n0 + wn * (FN * 16) + j * 16 + lc;
        float c1 = cv[col];
        float c2 = b2v[col];
        #pragma unroll
        for (int i = 0; i < FM; ++i)
            #pragma unroll
            for (int r = 0; r < 4; ++r) {
                float v1 = acc0[i][j][r] + c1;
                float v2 = acc1[i][j][r] + c2;
                acc0[i][j][r] = v1;
                float dd = v1 - v2;
                dsum += dd * dd;
            }
    }

    float* red = (float*)lds;
    red[tid] = dsum;
    __syncthreads();
    for (int o = 128; o > 0; o >>= 1) {
        if (tid < o) red[tid] += red[tid + o];
        __syncthreads();
    }
    if (tid == 0) partial_out[my * 2 + nx] = red[0];

    long baseT = (long)(m0 / NN) * ((long)N * NN) + (long)n0 * NN + (m0 % NN);
    write_tileT<BM, BN, FM, FN>(lds, acc0, C1T, baseT, NN, tid);
}

// ---------------------------------------------------------------------------
// gmix5_k: 5-phase pipelined (8 steps) + rank-1 epilogue (round 13).
// ---------------------------------------------------------------------------
template<int BM, int BN, int FM, int FN>
__global__ __launch_bounds__(256) void gmix5_k(
    const __hip_bfloat16* __restrict__ A0, const __hip_bfloat16* __restrict__ B0, int K0,
    const __hip_bfloat16* __restrict__ A1, const __hip_bfloat16* __restrict__ B1, int K1,
    const __hip_bfloat16* __restrict__ A2, const __hip_bfloat16* __restrict__ B2, int K2,
    const __hip_bfloat16* __restrict__ A3, const __hip_bfloat16* __restrict__ B3, int K3,
    const __hip_bfloat16* __restrict__ A4, const __hip_bfloat16* __restrict__ B4, int K4,
    const float* __restrict__ bv1, const float* __restrict__ b2v,
    const float* __restrict__ ars, const float* __restrict__ bw1s,
    __hip_bfloat16* __restrict__ C1, float* __restrict__ partial_out, int M, int N)
{
    __shared__ __attribute__((aligned(128))) char lds[2 * (BM + BN) * 128];

    const int d  = blockIdx.x;
    const int q  = d >> 3;
    const int nx = q & 1;
    const int my = (d & 7) + ((q >> 1) << 3);
    const int m0 = my * BM;
    const int n0 = nx * BN;

    const int tid  = threadIdx.x;
    const int wave = tid >> 6;
    const int lane = tid & 63;
    const int wm = wave >> 1, wn = wave & 1;

    f32x4 acc0[FM][FN], acc1[FM][FN];
    #pragma unroll
    for (int i = 0; i < FM; ++i)
        #pragma unroll
        for (int j = 0; j < FN; ++j) {
            acc0[i][j] = (f32x4){0.f, 0.f, 0.f, 0.f};
            acc1[i][j] = (f32x4){0.f, 0.f, 0.f, 0.f};
        }

    const __hip_bfloat16* pA[8] = {A0, A0, A0, A0, A1, A2, A3, A4};
    const __hip_bfloat16* pB[8] = {B0, B0, B0, B0, B1, B2, B3, B4};
    int pK[8]  = {K0, K0, K0, K0, K1, K2, K3, K4};
    int pk0[8] = {0, 64, 128, 192, 0, 0, 0, 0};
    pipe_run<BM, BN, FM, FN, 8, 7>(pA, pB, pK, pk0,
                                   lds, lds + (BM + BN) * 128,
                                   acc0, acc1, m0, n0, wave, lane);

    const int lc  = lane & 15;
    const int lr4 = (lane >> 4) << 2;
    const int node0 = m0 & (NN - 1);
    float dsum = 0.f;
    #pragma unroll
    for (int j = 0; j < FN; ++j) {
        int col = n0 + wn * (FN * 16) + j * 16 + lc;
        float c1 = bv1[col];
        float c2 = b2v[col];
        float bw = bw1s[col];
        #pragma unroll
        for (int i = 0; i < FM; ++i) {
            int rowl = wm * (FM * 16) + i * 16 + lr4;
            #pragma unroll
            for (int r = 0; r < 4; ++r) {
                float av = ars[node0 + rowl + r];
                float v1 = acc0[i][j][r] + c1 + av * bw;
                float v2 = acc1[i][j][r] + c2;
                acc0[i][j][r] = v1;
                float dd = v1 - v2;
                dsum += dd * dd;
            }
        }
    }

    float* red = (float*)lds;
    red[tid] = dsum;
    __syncthreads();
    for (int o = 128; o > 0; o >>= 1) {
        if (tid < o) red[tid] += red[tid + o];
        __syncthreads();
    }
    if (tid == 0) partial_out[my * 2 + nx] = red[0];

    write_tile<BM, BN, FM, FN>(lds, acc0, C1, (long)m0 * N + n0, N, tid);
}

// ---------------------------------------------------------------------------
// wave2_k (F): 6 pipelined steps (5 -> acc0, 1 -> acc1), plain grid.
// ---------------------------------------------------------------------------
template<int BM, int BN, int FM, int FN>
__global__ __launch_bounds__(256) void wave2_k(
    const __hip_bfloat16* __restrict__ A0, const __hip_bfloat16* __restrict__ B0, int K0,
    const __hip_bfloat16* __restrict__ A1, const __hip_bfloat16* __restrict__ B1, int K1,
    const __hip_bfloat16* __restrict__ A2, const __hip_bfloat16* __restrict__ B2, int K2,
    const float* __restrict__ cv, const float* __restrict__ b2v,
    __hip_bfloat16* __restrict__ C1, __hip_bfloat16* __restrict__ C2,
    float* __restrict__ partial_out, int M, int N)
{
    __shared__ __attribute__((aligned(128))) char lds[2 * (BM + BN) * 128];

    const int m0 = blockIdx.y * BM;
    const int n0 = blockIdx.x * BN;
    const int pidx = blockIdx.y * gridDim.x + blockIdx.x;

    const int tid  = threadIdx.x;
    const int wave = tid >> 6;
    const int lane = tid & 63;
    const int wn = wave & 1;

    f32x4 acc0[FM][FN], acc1[FM][FN];
    #pragma unroll
    for (int i = 0; i < FM; ++i)
        #pragma unroll
        for (int j = 0; j < FN; ++j) {
            acc0[i][j] = (f32x4){0.f, 0.f, 0.f, 0.f};
            acc1[i][j] = (f32x4){0.f, 0.f, 0.f, 0.f};
        }

    const __hip_bfloat16* pA[6] = {A0, A0, A0, A0, A1, A2};
    const __hip_bfloat16* pB[6] = {B0, B0, B0, B0, B1, B2};
    int pK[6]  = {K0, K0, K0, K0, K1, K2};
    int pk0[6] = {0, 64, 128, 192, 0, 0};
    pipe_run<BM, BN, FM, FN, 6, 5>(pA, pB, pK, pk0,
                                   lds, lds + (BM + BN) * 128,
                                   acc0, acc1, m0, n0, wave, lane);

    const int lc = lane & 15;
    float dsum = 0.f;
    #pragma unroll
    for (int j = 0; j < FN; ++j) {
        int col = n0 + wn * (FN * 16) + j * 16 + lc;
        float c1 = cv[col];
        float c2 = b2v[col];
        #pragma unroll
        for (int i = 0; i < FM; ++i)
            #pragma unroll
            for (int r = 0; r < 4; ++r) {
                float v1 = acc0[i][j][r] + c1;
                float v2 = acc1[i][j][r] + c2;
                acc0[i][j][r] = v1;
                acc1[i][j][r] = v2;
                float dd = v1 - v2;
                dsum += dd * dd;
            }
    }

    float* red = (float*)lds;
    red[tid] = dsum;
    __syncthreads();
    for (int o = 128; o > 0; o >>= 1) {
        if (tid < o) red[tid] += red[tid + o];
        __syncthreads();
    }
    if (tid == 0) partial_out[pidx] = red[0];

    write_tile<BM, BN, FM, FN>(lds, acc0, C1, (long)m0 * N + n0, N, tid);
    write_tile<BM, BN, FM, FN>(lds, acc1, C2, (long)m0 * N + n0, N, tid);
}

// ---------------------------------------------------------------------------
// final mix (th in-kernel): out = th*h + (1-th)*r, fp32 out
// ---------------------------------------------------------------------------
__global__ __launch_bounds__(256) void mixfinal_k(
    const unsigned short* __restrict__ h, const unsigned short* __restrict__ r,
    const float* __restrict__ partial_in, int np_in, float inv_in,
    float* __restrict__ out, long n4)
{
    __shared__ float sm[256];
    const float th = block_th(partial_in, np_in, inv_in, sm, (int)threadIdx.x);
    const float om = 1.f - th;
    long gid = (long)blockIdx.x * 256 + threadIdx.x;
    long stride = (long)gridDim.x * 256;
    for (long i = gid; i < n4; i += stride) {
        ushort4 hv = reinterpret_cast<const ushort4*>(h)[i];
        ushort4 rv = reinterpret_cast<const ushort4*>(r)[i];
        float4 o;
        o.x = th * bf2f(hv.x) + om * bf2f(rv.x);
        o.y = th * bf2f(hv.y) + om * bf2f(rv.y);
        o.z = th * bf2f(hv.z) + om * bf2f(rv.z);
        o.w = th * bf2f(hv.w) + om * bf2f(rv.w);
        reinterpret_cast<float4*>(out)[i] = o;
    }
}

// ---------------------------------------------------------------------------
extern "C" void kernel_launch(void* const* d_in, const int* in_sizes, int n_in,
                              void* d_out, int out_size, void* d_ws, size_t ws_size,
                              hipStream_t stream)
{
    const float* x       = (const float*)d_in[0];
    const float* adj     = (const float*)d_in[1];
    const float* Wres    = (const float*)d_in[2];
    const float* bres    = (const float*)d_in[3];
    const float* Wg0     = (const float*)d_in[4];
    const float* bg0     = (const float*)d_in[5];
    const float* Wrg0    = (const float*)d_in[6];
    const float* brg0    = (const float*)d_in[7];
    const float* logits0 = (const float*)d_in[8];
    const float* gumb0   = (const float*)d_in[9];
    const float* Wnl0    = (const float*)d_in[10];
    const float* bnl0    = (const float*)d_in[11];
    const float* Wwo0    = (const float*)d_in[12];
    const float* bwo0    = (const float*)d_in[13];
    const float* Wrw0    = (const float*)d_in[14];
    const float* brw0    = (const float*)d_in[15];
    const float* Wg1     = (const float*)d_in[16];
    const float* bg1     = (const float*)d_in[17];
    const float* Wrg1    = (const float*)d_in[18];
    const float* brg1    = (const float*)d_in[19];
    const float* logits1 = (const float*)d_in[20];
    const float* gumb1   = (const float*)d_in[21];
    const float* Wnl1    = (const float*)d_in[22];
    const float* bnl1    = (const float*)d_in[23];
    const float* Wwo1    = (const float*)d_in[24];
    const float* bwo1    = (const float*)d_in[25];
    const float* Wrw1    = (const float*)d_in[26];
    const float* brw1    = (const float*)d_in[27];

    float* out = (float*)d_out;

    // ---- workspace ----
    char* w = (char*)d_ws;
    auto alloc = [&](long bytes) { char* p = w; w += (bytes + 255) & ~255L; return p; };
    const long SLOT = (long)BNR * HH * 2;                 // 32 MB
    char* pool = alloc(5 * SLOT);                         // 160 MB
    __hip_bfloat16* Rbf  = (__hip_bfloat16*)alloc((long)BNR * DOUT * 2); // 8 MB
    __hip_bfloat16* adjb = (__hip_bfloat16*)alloc((long)NN * NN * 2);
    __hip_bfloat16* WT   = (__hip_bfloat16*)alloc(225280L * 2);
    float* partial0 = (float*)alloc(2048 * 4);
    float* partial1 = (float*)alloc(2048 * 4);
    float* partial2 = (float*)alloc(2048 * 4);
    float* partial3 = (float*)alloc(2048 * 4);
    float* bg0p    = (float*)alloc(256 * 4);
    float* brg0p   = (float*)alloc(256 * 4);
    float* crow0   = (float*)alloc(256 * 4);
    float* brgc1   = (float*)alloc(64 * 4);
    float* crow1   = (float*)alloc(64 * 4);
    float* cv0     = (float*)alloc(256 * 4);
    float* bv1g    = (float*)alloc(256 * 4);
    float* cv2     = (float*)alloc(64 * 4);
    float* ars     = (float*)alloc(512 * 4);
    float* bw1v    = (float*)alloc(256 * 4);
    float* bw1s    = (float*)alloc(256 * 4);

    auto S = [&](int i) { return pool + (long)i * SLOT; };
    __hip_bfloat16* xwrT = (__hip_bfloat16*)S(0);
    __hip_bfloat16* orw  = (__hip_bfloat16*)S(1);
    __hip_bfloat16* rw1  = (__hip_bfloat16*)(S(1) + (long)BNR * DOUT * 2);
    __hip_bfloat16* Radj = (__hip_bfloat16*)(S(1) + 2L * BNR * DOUT * 2);
    __hip_bfloat16* xg1  = (__hip_bfloat16*)S(2);
    __hip_bfloat16* T1x  = (__hip_bfloat16*)S(3);
    __hip_bfloat16* xbf  = (__hip_bfloat16*)S(4);
    __hip_bfloat16* xT   = (__hip_bfloat16*)(S(4) + (long)BNR * DIN * 2);
    __hip_bfloat16* T0   = (__hip_bfloat16*)(S(4) + 2L * BNR * DIN * 2);
    __hip_bfloat16* RbfT = (__hip_bfloat16*)(S(4) + 3L * BNR * DIN * 2);

    // transposed weights inside WT (element offsets)
    __hip_bfloat16* WresT   = WT;             // 64x64
    __hip_bfloat16* Wg0T    = WT + 4096;      // 256x64
    __hip_bfloat16* Wrg0T   = WT + 20480;     // 256x64  (NEGATED at prep)
    __hip_bfloat16* Wrw0T   = WT + 36864;     // 256x64
    __hip_bfloat16* Wg1T    = WT + 53248;     // 256x256 (th1 by sc1)
    __hip_bfloat16* Wrg1T   = WT + 118784;    // 256x64
    __hip_bfloat16* Wc1T    = WT + 135168;    // 64x256 (c1-scaled Wwo1^T; th2 by sc2)
    __hip_bfloat16* Wrw1T   = WT + 151552;    // 64x64
    __hip_bfloat16* Wg0pT   = WT + 155648;    // 256x64 (Wg0@(I+Wc0))^T; th0 sc0; th1 sc1
    __hip_bfloat16* Wrg0pT  = WT + 172032;    // 256x64 (Wrg0@(I+Wc0))^T; om0 sc0
    __hip_bfloat16* Wrgc1T  = WT + 188416;    // 64x64  (Wrg1@Wc1)^T; om2 sc2
    __hip_bfloat16* WcombT  = WT + 192512;    // 256x64 (th1*om0*Wrg0p + om1*Wrw0)^T by sc1
    __hip_bfloat16* WrwWg1T = WT + 208896;    // 256x64 (Wrw0@Wg1)^T; om1 by sc1

    const dim3 blk(256);
    const float invH = 1.0f / ((float)BNR * HH);
    const float invD = 1.0f / ((float)BNR * DOUT);

    // ---- prep (ONE launch) ----
    PrepArgs pa;
    pa.logits0 = logits0; pa.gumb0 = gumb0; pa.Wnl0 = Wnl0;
    pa.logits1 = logits1; pa.gumb1 = gumb1; pa.Wnl1 = Wnl1;
    pa.adj = adj; pa.adjb = (unsigned int*)adjb; pa.ars = ars;
    pa.x = x; pa.xbf = (unsigned short*)xbf; pa.xT = (unsigned short*)xT;

    WTArgs wa;
    wa.src[0] = Wres; wa.dst[0] = (unsigned short*)WresT; wa.ci[0] = 0; wa.sgn[0] = 1.f;  wa.R[0] = 64;  wa.C[0] = 64;
    wa.src[1] = Wg0;  wa.dst[1] = (unsigned short*)Wg0T;  wa.ci[1] = 0; wa.sgn[1] = 1.f;  wa.R[1] = 64;  wa.C[1] = 256;
    wa.src[2] = Wrg0; wa.dst[2] = (unsigned short*)Wrg0T; wa.ci[2] = 0; wa.sgn[2] = -1.f; wa.R[2] = 64;  wa.C[2] = 256;
    wa.src[3] = Wrw0; wa.dst[3] = (unsigned short*)Wrw0T; wa.ci[3] = 0; wa.sgn[3] = 1.f;  wa.R[3] = 64;  wa.C[3] = 256;
    wa.src[4] = Wg1;  wa.dst[4] = (unsigned short*)Wg1T;  wa.ci[4] = 0; wa.sgn[4] = 1.f;  wa.R[4] = 256; wa.C[4] = 256;
    wa.src[5] = Wrg1; wa.dst[5] = (unsigned short*)Wrg1T; wa.ci[5] = 0; wa.sgn[5] = 1.f;  wa.R[5] = 64;  wa.C[5] = 256;
    wa.src[6] = Wwo1; wa.dst[6] = (unsigned short*)Wc1T;  wa.ci[6] = 2; wa.sgn[6] = 1.f;  wa.R[6] = 256; wa.C[6] = 64;
    wa.src[7] = Wrw1; wa.dst[7] = (unsigned short*)Wrw1T; wa.ci[7] = 0; wa.sgn[7] = 1.f;  wa.R[7] = 64;  wa.C[7] = 64;

    WFArgs wf;
    wf.Wsrc[0] = Wg0;  wf.Wbig[0] = Wwo0; wf.ci[0] = 1; wf.incl[0] = 1; wf.N[0] = 256;
    wf.dst[0] = (unsigned short*)Wg0pT;
    wf.Wsrc[1] = Wrg0; wf.Wbig[1] = Wwo0; wf.ci[1] = 1; wf.incl[1] = 1; wf.N[1] = 256;
    wf.dst[1] = (unsigned short*)Wrg0pT;
    wf.Wsrc[2] = Wrg1; wf.Wbig[2] = Wwo1; wf.ci[2] = 2; wf.incl[2] = 0; wf.N[2] = 64;
    wf.dst[2] = (unsigned short*)Wrgc1T;
    wf.Wsrc[3] = Wrw0; wf.Wbig[3] = Wg1;  wf.ci[3] = 0; wf.incl[3] = 0; wf.N[3] = 256;
    wf.dst[3] = (unsigned short*)WrwWg1T;

    FVArgs fv;
    fv.W[0] = Wwo0; fv.ci[0] = 1; fv.v[0] = bg0;  fv.base[0] = bg0;     fv.out[0] = bg0p;  fv.K[0] = 256; fv.N[0] = 256;
    fv.W[1] = Wwo0; fv.ci[1] = 1; fv.v[1] = brg0; fv.base[1] = brg0;    fv.out[1] = brg0p; fv.K[1] = 256; fv.N[1] = 256;
    fv.W[2] = Wwo0; fv.ci[2] = 0; fv.v[2] = bnl0; fv.base[2] = bwo0;    fv.out[2] = crow0; fv.K[2] = 256; fv.N[2] = 256;
    fv.W[3] = Wwo1; fv.ci[3] = 2; fv.v[3] = brg1; fv.base[3] = nullptr; fv.out[3] = brgc1; fv.K[3] = 256; fv.N[3] = 64;
    fv.W[4] = Wwo1; fv.ci[4] = 0; fv.v[4] = bnl1; fv.base[4] = bwo1;    fv.out[4] = crow1; fv.K[4] = 256; fv.N[4] = 64;
    fv.W[5] = Wg1;  fv.ci[5] = 0; fv.v[5] = brw0; fv.base[5] = nullptr; fv.out[5] = bw1v;  fv.K[5] = 256; fv.N[5] = 256;

    hipLaunchKernelGGL(prep_k, dim3(NN + 8 * BB + 128 + 256 + 256), blk, 0, stream,
                       pa, wa, wf, fv);

    // res = x @ Wres + bres -> Rbf + RbfT
    hipLaunchKernelGGL((gemm_res_k<128, 64, 4, 2>), dim3(1, BNR / 128, 1), blk, 0, stream,
                       xbf, WresT, bres, Rbf, RbfT, BNR, DOUT, DIN);

    // T0 = adj@x AND Radj = adj@Rbf (fused)
    hipLaunchKernelGGL(t0radj_k, dim3(BB * 4), blk, 0, stream,
                       adjb, xT, RbfT, T0, Radj);

    // D0: diff0 partials only (pipelined)
    hipLaunchKernelGGL((dual1_k<64, 128, 2, 4>), dim3(2 * BNR / 64), blk, 0, stream,
                       T0, Wg0T, DIN, Rbf, Wrg0T, DOUT, bg0, brg0, partial0, BNR, HH);

    // sc0
    hipLaunchKernelGGL(sc0_k, dim3(64), blk, 0, stream, partial0, 2048, invH,
                       (unsigned short*)Wg0pT, (unsigned short*)Wrg0pT,
                       bg0p, brg0p, crow0, cv0);

    // W0: xwrT = [T0@(th0*Wg0p) + Rbf@(om0*Wrg0p) + cv0]^T ; diff vs Rbf@Wrw0+brw0
    hipLaunchKernelGGL((wave2T_k<64, 128, 2, 4>), dim3(2 * BNR / 64), blk, 0, stream,
                       T0, Wg0pT, DIN, Rbf, Wrg0pT, DOUT, Rbf, Wrw0T, DOUT,
                       cv0, brw0, xwrT, partial1, BNR, HH);

    // sc1
    hipLaunchKernelGGL(sc1_k, dim3(256), blk, 0, stream, partial1, 2048, invH,
                       (unsigned short*)Wg1T,
                       (const unsigned short*)Wrw0T, (const unsigned short*)Wrg0pT,
                       (unsigned short*)WcombT,
                       (unsigned short*)Wg0pT,
                       (unsigned short*)WrwWg1T,
                       bg1, brw0, cv0, bw1v, bv1g, bw1s);

    // T1x = adj @ xwr (batched, XCD-grouped, pipelined; 128x64 tiles)
    hipLaunchKernelGGL((gemm_bt_swz_k<128, 64, 4, 2, 4, 16, 8>), dim3(BB * 16), blk, 0, stream,
                       adjb, xwrT, T1x, NN, HH, NN, 0, (long)HH * NN, (long)NN * HH);

    // gmix5: xg1 (5 MFMA phases pipelined + rank-1), diff2 partials
    hipLaunchKernelGGL((gmix5_k<64, 128, 2, 4>), dim3(2 * BNR / 64), blk, 0, stream,
                       T1x, Wg1T, HH,
                       Radj, WrwWg1T, DOUT,
                       T0, Wg0pT, DIN,
                       Rbf, WcombT, DOUT,
                       Rbf, Wrg1T, DOUT,
                       bv1g, brg1, ars, bw1s, xg1, partial2, BNR, HH);

    // sc2
    hipLaunchKernelGGL(sc2_k, dim3(64), blk, 0, stream, partial2, 2048, invH,
                       (unsigned short*)Wc1T, (unsigned short*)Wrgc1T,
                       brgc1, crow1, cv2);

    // F: orw = xg1@(th2*Wc1) + Rbf@(om2*Wrgc1) + cv2 ; rw1 = Rbf@Wrw1 + brw1
    hipLaunchKernelGGL((wave2_k<64, 64, 2, 2>), dim3(1, BNR / 64), blk, 0, stream,
                       xg1, Wc1T, HH, Rbf, Wrgc1T, DOUT, Rbf, Wrw1T, DIN,
                       cv2, brw1, orw, rw1, partial3, BNR, DOUT);

    // final mix -> fp32 out
    hipLaunchKernelGGL(mixfinal_k, dim3(2048), blk, 0, stream,
                       (const unsigned short*)orw, (const unsigned short*)rw1,
                       partial3, 1024, invD, out, (long)BNR * DOUT / 4);
}